// Round 1
// baseline (355.755 us; speedup 1.0000x reference)
//
#include <hip/hip_runtime.h>
#include <hip/hip_bf16.h>
#include <math.h>

typedef __attribute__((ext_vector_type(8))) short short8;
typedef __attribute__((ext_vector_type(8))) __bf16 bf16x8;
typedef __attribute__((ext_vector_type(4))) float f32x4;

#define D_MODEL 1024
#define NUM_HEADS 16
#define D_HEAD 64
#define BATCH 2
#define SEQ 2048
#define BH (BATCH * NUM_HEADS)   // 32
#define MTOT (BATCH * SEQ)       // 4096

__device__ inline f32x4 mfma16(short8 a, short8 b, f32x4 c) {
  return __builtin_amdgcn_mfma_f32_16x16x32_bf16(
      __builtin_bit_cast(bf16x8, a), __builtin_bit_cast(bf16x8, b), c, 0, 0, 0);
}

__device__ inline unsigned short f2b(float f) {
  __hip_bfloat16 h = __float2bfloat16(f);
  return __builtin_bit_cast(unsigned short, h);
}
__device__ inline float b2f(unsigned short u) {
  return __bfloat162float(__builtin_bit_cast(__hip_bfloat16, u));
}

// ---------------- fp32 -> bf16 conversion (vectorized) ----------------
__global__ void cvt_f32_bf16(const float* __restrict__ in,
                             unsigned short* __restrict__ out, int n) {
  int i = (blockIdx.x * 256 + threadIdx.x) * 4;
  if (i >= n) return;
  float4 v = *(const float4*)(in + i);
  ushort4 o;
  o.x = f2b(v.x); o.y = f2b(v.y); o.z = f2b(v.z); o.w = f2b(v.w);
  *(ushort4*)(out + i) = o;
}

// ---------------- RoPE cos/sin tables: [SEQ][32] each ----------------
__global__ void trig_kernel(float* __restrict__ tcos, float* __restrict__ tsin) {
  int idx = blockIdx.x * 256 + threadIdx.x;  // SEQ*32 threads
  int i = idx & 31;
  int s = idx >> 5;
  float inv = powf(10000.0f, -(float)i / 32.0f);
  float t = (float)s * inv;
  tcos[idx] = cosf(t);
  tsin[idx] = sinf(t);
}

// ---------------- GEMM: C[M,N] = A[M,K] @ B[N,K]^T + bias ----------------
// EPI 0: write bf16 to [B,H,S,Dh]   (Q, K)
// EPI 1: write bf16 to [B,H,Dh,S]   (V transposed)
// EPI 2: write fp32 to [M, N]       (final output)
template <int EPI>
__global__ __launch_bounds__(256) void gemm_bt(
    const unsigned short* __restrict__ A,  // [M,K] bf16
    const unsigned short* __restrict__ B,  // [N,K] bf16
    const float* __restrict__ bias,        // [N]
    unsigned short* __restrict__ outb,
    float* __restrict__ outf,
    int K) {
  __shared__ unsigned short As[64][32];
  __shared__ unsigned short Bs[64][32];
  const int bm = blockIdx.y * 64;
  const int bn = blockIdx.x * 64;
  const int tid = threadIdx.x;
  const int lane = tid & 63;
  const int wid = tid >> 6;
  const int wr = (wid >> 1) * 32, wc = (wid & 1) * 32;
  const int srow = tid >> 2, scol = (tid & 3) * 8;
  const int fr = lane & 15, fk = (lane >> 4) * 8;
  f32x4 acc[2][2] = {};

  for (int k0 = 0; k0 < K; k0 += 32) {
    *(short8*)&As[srow][scol] = *(const short8*)&A[(size_t)(bm + srow) * K + k0 + scol];
    *(short8*)&Bs[srow][scol] = *(const short8*)&B[(size_t)(bn + srow) * K + k0 + scol];
    __syncthreads();
    short8 a0 = *(const short8*)&As[wr + fr][fk];
    short8 a1 = *(const short8*)&As[wr + 16 + fr][fk];
    short8 b0 = *(const short8*)&Bs[wc + fr][fk];
    short8 b1 = *(const short8*)&Bs[wc + 16 + fr][fk];
    acc[0][0] = mfma16(a0, b0, acc[0][0]);
    acc[0][1] = mfma16(a0, b1, acc[0][1]);
    acc[1][0] = mfma16(a1, b0, acc[1][0]);
    acc[1][1] = mfma16(a1, b1, acc[1][1]);
    __syncthreads();
  }

  for (int mi = 0; mi < 2; mi++)
    for (int ni = 0; ni < 2; ni++)
      for (int r = 0; r < 4; r++) {
        int row = bm + wr + mi * 16 + (lane >> 4) * 4 + r;
        int col = bn + wc + ni * 16 + fr;
        float v = acc[mi][ni][r] + bias[col];
        if (EPI == 2) {
          outf[(size_t)row * D_MODEL + col] = v;
        } else {
          int b = row >> 11, s = row & (SEQ - 1);
          int h = col >> 6, dh = col & 63;
          if (EPI == 0)
            outb[(((size_t)(b * NUM_HEADS + h)) * SEQ + s) * 64 + dh] = f2b(v);
          else
            outb[(((size_t)(b * NUM_HEADS + h)) * 64 + dh) * SEQ + s] = f2b(v);
        }
      }
}

// ---------------- RoPE (in place on [BH,S,64] bf16) ----------------
__global__ void rope_kernel(unsigned short* __restrict__ X,
                            const float* __restrict__ tc,
                            const float* __restrict__ ts) {
  int idx = blockIdx.x * 256 + threadIdx.x;  // BH*SEQ*32 threads
  int i = idx & 31;
  int s = (idx >> 5) & (SEQ - 1);
  int bh = idx >> 16;  // 32*2048 = 2^16
  unsigned short* p = X + (((size_t)bh * SEQ) + s) * 64;
  float x0 = b2f(p[i]);
  float x1 = b2f(p[i + 32]);
  float c = tc[s * 32 + i], sn = ts[s * 32 + i];
  p[i] = f2b(x0 * c - x1 * sn);
  p[i + 32] = f2b(x1 * c + x0 * sn);
}

// ---------------- causal flash attention ----------------
// Q,K: [BH,S,64] bf16 ; Vt: [BH,64,S] bf16 ; ctx out: [B,S,H*64] bf16
__global__ __launch_bounds__(64) void flash_attn(
    const unsigned short* __restrict__ Q,
    const unsigned short* __restrict__ Km,
    const unsigned short* __restrict__ Vt,
    unsigned short* __restrict__ ctx) {
  __shared__ unsigned short Plds[16][32];
  const int qb = blockIdx.x;   // S/16 q-blocks
  const int bh = blockIdx.y;   // 32
  const int lane = threadIdx.x;
  const int qbase = qb * 16;
  const int fr = lane & 15;
  const int fk = (lane >> 4) * 8;

  const unsigned short* Qp = Q + (size_t)bh * SEQ * 64;
  const unsigned short* Kp = Km + (size_t)bh * SEQ * 64;
  const unsigned short* Vp = Vt + (size_t)bh * 64 * SEQ;

  short8 qf0 = *(const short8*)&Qp[(qbase + fr) * 64 + fk];
  short8 qf1 = *(const short8*)&Qp[(qbase + fr) * 64 + 32 + fk];

  float mrow[4], lrow[4];
  for (int r = 0; r < 4; r++) { mrow[r] = -INFINITY; lrow[r] = 0.f; }
  f32x4 cacc[4] = {};

  for (int kbase = 0; kbase < qbase + 16; kbase += 32) {
    f32x4 sacc[2] = {};
    for (int n = 0; n < 2; n++) {
      int kcol = kbase + n * 16 + fr;
      short8 kf0 = *(const short8*)&Kp[kcol * 64 + fk];
      short8 kf1 = *(const short8*)&Kp[kcol * 64 + 32 + fk];
      sacc[n] = mfma16(qf0, kf0, sacc[n]);
      sacc[n] = mfma16(qf1, kf1, sacc[n]);
    }
    // scale + causal mask
    float sv[2][4];
    for (int n = 0; n < 2; n++)
      for (int r = 0; r < 4; r++) {
        int row = qbase + (lane >> 4) * 4 + r;
        int col = kbase + n * 16 + fr;
        float s = sacc[n][r] * 0.125f;
        sv[n][r] = (col <= row) ? s : -INFINITY;
      }
    // row max across the 16-lane group, both halves
    float p[2][4];
    for (int r = 0; r < 4; r++) {
      float t = fmaxf(sv[0][r], sv[1][r]);
      for (int off = 1; off < 16; off <<= 1)
        t = fmaxf(t, __shfl_xor(t, off));
      float mnew = fmaxf(mrow[r], t);
      float corr = expf(mrow[r] - mnew);
      float rs = 0.f;
      for (int n = 0; n < 2; n++) {
        p[n][r] = expf(sv[n][r] - mnew);
        rs += p[n][r];
      }
      for (int off = 1; off < 16; off <<= 1)
        rs += __shfl_xor(rs, off);
      lrow[r] = lrow[r] * corr + rs;
      mrow[r] = mnew;
      for (int db = 0; db < 4; db++) cacc[db][r] *= corr;
    }
    // P tile -> LDS (C-layout) -> A-fragment layout
    for (int n = 0; n < 2; n++)
      for (int r = 0; r < 4; r++)
        Plds[(lane >> 4) * 4 + r][n * 16 + fr] = f2b(p[n][r]);
    __syncthreads();
    short8 pa = *(const short8*)&Plds[fr][fk];
    for (int db = 0; db < 4; db++) {
      short8 vf = *(const short8*)&Vp[(size_t)(db * 16 + fr) * SEQ + kbase + fk];
      cacc[db] = mfma16(pa, vf, cacc[db]);
    }
    __syncthreads();
  }

  int b = bh >> 4, h = bh & 15;
  for (int db = 0; db < 4; db++)
    for (int r = 0; r < 4; r++) {
      int row = qbase + (lane >> 4) * 4 + r;
      float v = cacc[db][r] / lrow[r];
      ctx[(((size_t)b * SEQ) + row) * D_MODEL + h * 64 + db * 16 + fr] = f2b(v);
    }
}

extern "C" void kernel_launch(void* const* d_in, const int* in_sizes, int n_in,
                              void* d_out, int out_size, void* d_ws, size_t ws_size,
                              hipStream_t stream) {
  const float* x  = (const float*)d_in[0];
  const float* Wq = (const float*)d_in[1];
  const float* bq = (const float*)d_in[2];
  const float* Wk = (const float*)d_in[3];
  const float* bk = (const float*)d_in[4];
  const float* Wv = (const float*)d_in[5];
  const float* bv = (const float*)d_in[6];
  const float* Wo = (const float*)d_in[7];
  const float* bo = (const float*)d_in[8];
  float* out = (float*)d_out;

  char* ws = (char*)d_ws;
  size_t off = 0;
  auto alloc = [&](size_t bytes) {
    char* p = ws + off;
    off += (bytes + 255) & ~(size_t)255;
    return p;
  };
  unsigned short* xb   = (unsigned short*)alloc((size_t)MTOT * D_MODEL * 2);
  unsigned short* wqb  = (unsigned short*)alloc((size_t)D_MODEL * D_MODEL * 2);
  unsigned short* wkb  = (unsigned short*)alloc((size_t)D_MODEL * D_MODEL * 2);
  unsigned short* wvb  = (unsigned short*)alloc((size_t)D_MODEL * D_MODEL * 2);
  unsigned short* wob  = (unsigned short*)alloc((size_t)D_MODEL * D_MODEL * 2);
  unsigned short* Qb   = (unsigned short*)alloc((size_t)BH * SEQ * 64 * 2);
  unsigned short* Kb   = (unsigned short*)alloc((size_t)BH * SEQ * 64 * 2);
  unsigned short* Vt   = (unsigned short*)alloc((size_t)BH * 64 * SEQ * 2);
  unsigned short* ctxb = (unsigned short*)alloc((size_t)MTOT * D_MODEL * 2);
  float* tcos = (float*)alloc((size_t)SEQ * 32 * 4);
  float* tsin = (float*)alloc((size_t)SEQ * 32 * 4);

  int nx = MTOT * D_MODEL;     // 4,194,304
  int nw = D_MODEL * D_MODEL;  // 1,048,576
  cvt_f32_bf16<<<nx / 1024, 256, 0, stream>>>(x, xb, nx);
  cvt_f32_bf16<<<nw / 1024, 256, 0, stream>>>(Wq, wqb, nw);
  cvt_f32_bf16<<<nw / 1024, 256, 0, stream>>>(Wk, wkb, nw);
  cvt_f32_bf16<<<nw / 1024, 256, 0, stream>>>(Wv, wvb, nw);
  cvt_f32_bf16<<<nw / 1024, 256, 0, stream>>>(Wo, wob, nw);
  trig_kernel<<<SEQ * 32 / 256, 256, 0, stream>>>(tcos, tsin);

  dim3 gg(D_MODEL / 64, MTOT / 64);
  gemm_bt<0><<<gg, 256, 0, stream>>>(xb, wqb, bq, Qb, nullptr, D_MODEL);
  gemm_bt<0><<<gg, 256, 0, stream>>>(xb, wkb, bk, Kb, nullptr, D_MODEL);
  gemm_bt<1><<<gg, 256, 0, stream>>>(xb, wvb, bv, Vt, nullptr, D_MODEL);

  rope_kernel<<<BH * SEQ * 32 / 256, 256, 0, stream>>>(Qb, tcos, tsin);
  rope_kernel<<<BH * SEQ * 32 / 256, 256, 0, stream>>>(Kb, tcos, tsin);

  flash_attn<<<dim3(SEQ / 16, BH), 64, 0, stream>>>(Qb, Kb, Vt, ctxb);

  gemm_bt<2><<<gg, 256, 0, stream>>>(ctxb, wob, bo, nullptr, out, D_MODEL);
}

// Round 2
// 264.964 us; speedup vs baseline: 1.3427x; 1.3427x over previous
//
#include <hip/hip_runtime.h>
#include <hip/hip_bf16.h>
#include <math.h>

typedef __attribute__((ext_vector_type(8))) short short8;
typedef __attribute__((ext_vector_type(8))) __bf16 bf16x8;
typedef __attribute__((ext_vector_type(4))) float f32x4;

#define D_MODEL 1024
#define NUM_HEADS 16
#define D_HEAD 64
#define BATCH 2
#define SEQ 2048
#define BH (BATCH * NUM_HEADS)   // 32
#define MTOT (BATCH * SEQ)       // 4096

__device__ inline f32x4 mfma16(short8 a, short8 b, f32x4 c) {
  return __builtin_amdgcn_mfma_f32_16x16x32_bf16(
      __builtin_bit_cast(bf16x8, a), __builtin_bit_cast(bf16x8, b), c, 0, 0, 0);
}

__device__ inline unsigned short f2b(float f) {
  __hip_bfloat16 h = __float2bfloat16(f);
  return __builtin_bit_cast(unsigned short, h);
}
__device__ inline float b2f(unsigned short u) {
  return __bfloat162float(__builtin_bit_cast(__hip_bfloat16, u));
}

#define GLOAD_LDS16(gaddr, laddr)                                              \
  __builtin_amdgcn_global_load_lds(                                            \
      (const __attribute__((address_space(1))) void*)(gaddr),                  \
      (__attribute__((address_space(3))) void*)(laddr), 16, 0, 0)

// ---------------- fp32 -> bf16 conversion (vectorized) ----------------
__global__ void cvt_f32_bf16(const float* __restrict__ in,
                             unsigned short* __restrict__ out, int n) {
  int i = (blockIdx.x * 256 + threadIdx.x) * 4;
  if (i >= n) return;
  float4 v = *(const float4*)(in + i);
  ushort4 o;
  o.x = f2b(v.x); o.y = f2b(v.y); o.z = f2b(v.z); o.w = f2b(v.w);
  *(ushort4*)(out + i) = o;
}

// ---------------- RoPE cos/sin tables: [SEQ][32] each ----------------
__global__ void trig_kernel(float* __restrict__ tcos, float* __restrict__ tsin) {
  int idx = blockIdx.x * 256 + threadIdx.x;  // SEQ*32 threads
  int i = idx & 31;
  int s = idx >> 5;
  float inv = powf(10000.0f, -(float)i / 32.0f);
  float t = (float)s * inv;
  tcos[idx] = cosf(t);
  tsin[idx] = sinf(t);
}

// ---------------- GEMM: C[M,N] = A[M,K] @ B[N,K]^T + bias ----------------
// m97-style: 128x128 tile, BK=32, 4 waves x (64x64), global_load_lds staging.
// EPI 0: write bf16 to [B,H,S,Dh]   (Q, K)
// EPI 1: write bf16 to [B,H,Dh,S]   (V transposed)
// EPI 2: write fp32 to [M, N]       (final output)
template <int EPI>
__global__ __launch_bounds__(256) void gemm_bt(
    const unsigned short* __restrict__ A,  // [M,K] bf16
    const unsigned short* __restrict__ B,  // [N,K] bf16
    const float* __restrict__ bias,        // [N]
    unsigned short* __restrict__ outb,
    float* __restrict__ outf,
    int K) {
  __shared__ unsigned short As[128][32];
  __shared__ unsigned short Bs[128][32];
  const int bm = blockIdx.y * 128;
  const int bn = blockIdx.x * 128;
  const int tid = threadIdx.x;
  const int lane = tid & 63;
  const int w = tid >> 6;
  const int wr = (w >> 1) * 64, wc = (w & 1) * 64;
  const int fr = lane & 15;
  const int g = lane >> 4;
  const int fk = g * 8;
  // staging geometry: chunk c covers LDS bytes [c*1024, c*1024+1024);
  // lane l -> row c*16 + l/4, col-short (l&3)*8. Wave w stages chunks 2w,2w+1.
  const int srow0 = (w * 2) * 16 + (lane >> 2);
  const int srow1 = (w * 2 + 1) * 16 + (lane >> 2);
  const int scol = (lane & 3) * 8;

  f32x4 acc[4][4] = {};

  for (int k0 = 0; k0 < K; k0 += 32) {
    GLOAD_LDS16(&A[(size_t)(bm + srow0) * K + k0 + scol], &As[srow0][scol]);
    GLOAD_LDS16(&A[(size_t)(bm + srow1) * K + k0 + scol], &As[srow1][scol]);
    GLOAD_LDS16(&B[(size_t)(bn + srow0) * K + k0 + scol], &Bs[srow0][scol]);
    GLOAD_LDS16(&B[(size_t)(bn + srow1) * K + k0 + scol], &Bs[srow1][scol]);
    __syncthreads();
    short8 af[4], bf[4];
    for (int mi = 0; mi < 4; mi++)
      af[mi] = *(const short8*)&As[wr + mi * 16 + fr][fk];
    for (int ni = 0; ni < 4; ni++)
      bf[ni] = *(const short8*)&Bs[wc + ni * 16 + fr][fk];
    for (int mi = 0; mi < 4; mi++)
      for (int ni = 0; ni < 4; ni++)
        acc[mi][ni] = mfma16(af[mi], bf[ni], acc[mi][ni]);
    __syncthreads();
  }

  for (int mi = 0; mi < 4; mi++)
    for (int ni = 0; ni < 4; ni++)
      for (int r = 0; r < 4; r++) {
        int row = bm + wr + mi * 16 + g * 4 + r;
        int col = bn + wc + ni * 16 + fr;
        float v = acc[mi][ni][r] + bias[col];
        if (EPI == 2) {
          outf[(size_t)row * D_MODEL + col] = v;
        } else {
          int b = row >> 11, s = row & (SEQ - 1);
          int h = col >> 6, dh = col & 63;
          if (EPI == 0)
            outb[(((size_t)(b * NUM_HEADS + h)) * SEQ + s) * 64 + dh] = f2b(v);
          else
            outb[(((size_t)(b * NUM_HEADS + h)) * 64 + dh) * SEQ + s] = f2b(v);
        }
      }
}

// ---------------- RoPE (in place on [BH,S,64] bf16) ----------------
__global__ void rope_kernel(unsigned short* __restrict__ X,
                            const float* __restrict__ tc,
                            const float* __restrict__ ts) {
  int idx = blockIdx.x * 256 + threadIdx.x;  // BH*SEQ*32 threads
  int i = idx & 31;
  int s = (idx >> 5) & (SEQ - 1);
  int bh = idx >> 16;
  unsigned short* p = X + (((size_t)bh * SEQ) + s) * 64;
  float x0 = b2f(p[i]);
  float x1 = b2f(p[i + 32]);
  float c = tc[s * 32 + i], sn = ts[s * 32 + i];
  p[i] = f2b(x0 * c - x1 * sn);
  p[i + 32] = f2b(x1 * c + x0 * sn);
}

// ---------------- causal flash attention ----------------
// 4 waves / block, QBLK=64 (16 q-rows per wave), KVBLK=64 staged in LDS.
// Q,K: [BH,S,64] bf16 ; Vt: [BH,64,S] bf16 ; ctx out: [B,S,H*64] bf16
#define KPAD 72  // 144B row stride: 16B-aligned, 2-way max bank aliasing

__global__ __launch_bounds__(256) void flash_attn(
    const unsigned short* __restrict__ Q,
    const unsigned short* __restrict__ Km,
    const unsigned short* __restrict__ Vt,
    unsigned short* __restrict__ ctx) {
  __shared__ unsigned short Ks[64][KPAD];      // [key][dh]
  __shared__ unsigned short Vs[64][KPAD];      // [dh][key]
  __shared__ unsigned short Ps[4][16][KPAD];   // per-wave P
  const int qb = blockIdx.x;   // S/64
  const int bh = blockIdx.y;   // 32
  const int tid = threadIdx.x;
  const int lane = tid & 63;
  const int w = tid >> 6;
  const int qbase = qb * 64;
  const int fr = lane & 15;
  const int g = lane >> 4;
  const int fk = g * 8;

  const unsigned short* Qp = Q + (size_t)bh * SEQ * 64;
  const unsigned short* Kp = Km + (size_t)bh * SEQ * 64;
  const unsigned short* Vp = Vt + (size_t)bh * 64 * SEQ;

  const int qrow0 = qbase + w * 16;
  const int wmax = qrow0 + 15;
  short8 qf0 = *(const short8*)&Qp[(qrow0 + fr) * 64 + fk];
  short8 qf1 = *(const short8*)&Qp[(qrow0 + fr) * 64 + 32 + fk];

  float mrow[4], lrow[4];
  for (int r = 0; r < 4; r++) { mrow[r] = -INFINITY; lrow[r] = 0.f; }
  f32x4 cacc[4] = {};

  for (int kbase = 0; kbase < qbase + 64; kbase += 64) {
    // cooperative staging: 64x64 shorts each for K and Vt
    for (int i = 0; i < 2; i++) {
      int c = tid + 256 * i;
      int row = c >> 3, col = (c & 7) * 8;
      *(short8*)&Ks[row][col] = *(const short8*)&Kp[(size_t)(kbase + row) * 64 + col];
      *(short8*)&Vs[row][col] = *(const short8*)&Vp[(size_t)row * SEQ + kbase + col];
    }
    __syncthreads();

    // scores: wave's 16 rows x 64 keys
    f32x4 sacc[4] = {};
    for (int n = 0; n < 4; n++) {
      if (kbase + n * 16 <= wmax) {  // wave-uniform: skip fully-masked tiles
        short8 kf0 = *(const short8*)&Ks[n * 16 + fr][fk];
        short8 kf1 = *(const short8*)&Ks[n * 16 + fr][32 + fk];
        sacc[n] = mfma16(qf0, kf0, sacc[n]);
        sacc[n] = mfma16(qf1, kf1, sacc[n]);
      }
    }

    // online softmax (per r: one 16-lane reduce over 64 keys)
    float p[4][4];
    for (int r = 0; r < 4; r++) {
      int row = qrow0 + g * 4 + r;
      float sv[4];
      float t = -INFINITY;
      for (int n = 0; n < 4; n++) {
        int col = kbase + n * 16 + fr;
        sv[n] = (col <= row) ? sacc[n][r] * 0.125f : -INFINITY;
        t = fmaxf(t, sv[n]);
      }
      for (int off = 1; off < 16; off <<= 1) t = fmaxf(t, __shfl_xor(t, off));
      float mnew = fmaxf(mrow[r], t);
      float corr = __expf(mrow[r] - mnew);
      float rs = 0.f;
      for (int n = 0; n < 4; n++) { p[n][r] = __expf(sv[n] - mnew); rs += p[n][r]; }
      for (int off = 1; off < 16; off <<= 1) rs += __shfl_xor(rs, off);
      lrow[r] = lrow[r] * corr + rs;
      mrow[r] = mnew;
      for (int db = 0; db < 4; db++) cacc[db][r] *= corr;
    }

    // P tile -> LDS (per-wave private; in-wave write->read, compiler waits)
    for (int n = 0; n < 4; n++)
      for (int r = 0; r < 4; r++)
        Ps[w][g * 4 + r][n * 16 + fr] = f2b(p[n][r]);

    for (int ks = 0; ks < 2; ks++) {
      if (kbase + ks * 32 <= wmax) {  // wave-uniform: skip all-zero P chunks
        short8 pa = *(const short8*)&Ps[w][fr][ks * 32 + fk];
        for (int db = 0; db < 4; db++) {
          short8 vf = *(const short8*)&Vs[db * 16 + fr][ks * 32 + fk];
          cacc[db] = mfma16(pa, vf, cacc[db]);
        }
      }
    }
    __syncthreads();
  }

  int b = bh >> 4, h = bh & 15;
  for (int r = 0; r < 4; r++) {
    int row = qrow0 + g * 4 + r;
    float inv = 1.f / lrow[r];
    for (int db = 0; db < 4; db++) {
      float v = cacc[db][r] * inv;
      ctx[(((size_t)b * SEQ) + row) * D_MODEL + h * 64 + db * 16 + fr] = f2b(v);
    }
  }
}

extern "C" void kernel_launch(void* const* d_in, const int* in_sizes, int n_in,
                              void* d_out, int out_size, void* d_ws, size_t ws_size,
                              hipStream_t stream) {
  const float* x  = (const float*)d_in[0];
  const float* Wq = (const float*)d_in[1];
  const float* bq = (const float*)d_in[2];
  const float* Wk = (const float*)d_in[3];
  const float* bk = (const float*)d_in[4];
  const float* Wv = (const float*)d_in[5];
  const float* bv = (const float*)d_in[6];
  const float* Wo = (const float*)d_in[7];
  const float* bo = (const float*)d_in[8];
  float* out = (float*)d_out;

  char* ws = (char*)d_ws;
  size_t off = 0;
  auto alloc = [&](size_t bytes) {
    char* p = ws + off;
    off += (bytes + 255) & ~(size_t)255;
    return p;
  };
  unsigned short* xb   = (unsigned short*)alloc((size_t)MTOT * D_MODEL * 2);
  unsigned short* wqb  = (unsigned short*)alloc((size_t)D_MODEL * D_MODEL * 2);
  unsigned short* wkb  = (unsigned short*)alloc((size_t)D_MODEL * D_MODEL * 2);
  unsigned short* wvb  = (unsigned short*)alloc((size_t)D_MODEL * D_MODEL * 2);
  unsigned short* wob  = (unsigned short*)alloc((size_t)D_MODEL * D_MODEL * 2);
  unsigned short* Qb   = (unsigned short*)alloc((size_t)BH * SEQ * 64 * 2);
  unsigned short* Kb   = (unsigned short*)alloc((size_t)BH * SEQ * 64 * 2);
  unsigned short* Vt   = (unsigned short*)alloc((size_t)BH * 64 * SEQ * 2);
  unsigned short* ctxb = (unsigned short*)alloc((size_t)MTOT * D_MODEL * 2);
  float* tcos = (float*)alloc((size_t)SEQ * 32 * 4);
  float* tsin = (float*)alloc((size_t)SEQ * 32 * 4);

  int nx = MTOT * D_MODEL;
  int nw = D_MODEL * D_MODEL;
  cvt_f32_bf16<<<nx / 1024, 256, 0, stream>>>(x, xb, nx);
  cvt_f32_bf16<<<nw / 1024, 256, 0, stream>>>(Wq, wqb, nw);
  cvt_f32_bf16<<<nw / 1024, 256, 0, stream>>>(Wk, wkb, nw);
  cvt_f32_bf16<<<nw / 1024, 256, 0, stream>>>(Wv, wvb, nw);
  cvt_f32_bf16<<<nw / 1024, 256, 0, stream>>>(Wo, wob, nw);
  trig_kernel<<<SEQ * 32 / 256, 256, 0, stream>>>(tcos, tsin);

  dim3 gg(D_MODEL / 128, MTOT / 128);
  gemm_bt<0><<<gg, 256, 0, stream>>>(xb, wqb, bq, Qb, nullptr, D_MODEL);
  gemm_bt<0><<<gg, 256, 0, stream>>>(xb, wkb, bk, Kb, nullptr, D_MODEL);
  gemm_bt<1><<<gg, 256, 0, stream>>>(xb, wvb, bv, Vt, nullptr, D_MODEL);

  rope_kernel<<<BH * SEQ * 32 / 256, 256, 0, stream>>>(Qb, tcos, tsin);
  rope_kernel<<<BH * SEQ * 32 / 256, 256, 0, stream>>>(Kb, tcos, tsin);

  flash_attn<<<dim3(SEQ / 64, BH), 256, 0, stream>>>(Qb, Kb, Vt, ctxb);

  gemm_bt<2><<<gg, 256, 0, stream>>>(ctxb, wob, bo, nullptr, out, D_MODEL);
}

// Round 3
// 218.555 us; speedup vs baseline: 1.6278x; 1.2123x over previous
//
#include <hip/hip_runtime.h>
#include <hip/hip_bf16.h>
#include <math.h>

typedef __attribute__((ext_vector_type(8))) short short8;
typedef __attribute__((ext_vector_type(8))) __bf16 bf16x8;
typedef __attribute__((ext_vector_type(4))) float f32x4;

#define D_MODEL 1024
#define NUM_HEADS 16
#define D_HEAD 64
#define BATCH 2
#define SEQ 2048
#define BH (BATCH * NUM_HEADS)   // 32
#define MTOT (BATCH * SEQ)       // 4096

__device__ inline f32x4 mfma16(short8 a, short8 b, f32x4 c) {
  return __builtin_amdgcn_mfma_f32_16x16x32_bf16(
      __builtin_bit_cast(bf16x8, a), __builtin_bit_cast(bf16x8, b), c, 0, 0, 0);
}

__device__ inline unsigned short f2b(float f) {
  __hip_bfloat16 h = __float2bfloat16(f);
  return __builtin_bit_cast(unsigned short, h);
}
__device__ inline float b2f(unsigned short u) {
  return __bfloat162float(__builtin_bit_cast(__hip_bfloat16, u));
}

#define GLOAD_LDS16(gaddr, laddr)                                              \
  __builtin_amdgcn_global_load_lds(                                            \
      (const __attribute__((address_space(1))) void*)(gaddr),                  \
      (__attribute__((address_space(3))) void*)(laddr), 16, 0, 0)

// ---------------- fp32 -> bf16 conversion (vectorized) ----------------
__global__ void cvt_f32_bf16(const float* __restrict__ in,
                             unsigned short* __restrict__ out, int n) {
  int i = (blockIdx.x * 256 + threadIdx.x) * 4;
  if (i >= n) return;
  float4 v = *(const float4*)(in + i);
  ushort4 o;
  o.x = f2b(v.x); o.y = f2b(v.y); o.z = f2b(v.z); o.w = f2b(v.w);
  *(ushort4*)(out + i) = o;
}

// 4 equal-size weight matrices in one launch (blockIdx.y selects)
__global__ void cvt4_f32_bf16(const float* __restrict__ w0, const float* __restrict__ w1,
                              const float* __restrict__ w2, const float* __restrict__ w3,
                              unsigned short* __restrict__ o0, unsigned short* __restrict__ o1,
                              unsigned short* __restrict__ o2, unsigned short* __restrict__ o3,
                              int n) {
  const float* in; unsigned short* out;
  switch (blockIdx.y) {
    case 0: in = w0; out = o0; break;
    case 1: in = w1; out = o1; break;
    case 2: in = w2; out = o2; break;
    default: in = w3; out = o3; break;
  }
  int i = (blockIdx.x * 256 + threadIdx.x) * 4;
  if (i >= n) return;
  float4 v = *(const float4*)(in + i);
  ushort4 o;
  o.x = f2b(v.x); o.y = f2b(v.y); o.z = f2b(v.z); o.w = f2b(v.w);
  *(ushort4*)(out + i) = o;
}

// ---------------- RoPE table: interleaved (cos,sin), [SEQ][32] ----------------
__global__ void trig_kernel(float2* __restrict__ tct) {
  int idx = blockIdx.x * 256 + threadIdx.x;  // SEQ*32 threads
  int i = idx & 31;
  int s = idx >> 5;
  float inv = powf(10000.0f, -(float)i / 32.0f);
  float t = (float)s * inv;
  tct[idx] = make_float2(cosf(t), sinf(t));
}

// ---------------- GEMM: C[M,N] = A[M,K] @ B[N,K]^T + bias ----------------
// m97-style: 128x128 tile, BK=32, 4 waves x (64x64), global_load_lds staging.
// EPI 0: Q -> [B,H,S,Dh] bf16, RoPE applied, scaled by 0.125
// EPI 1: K -> [B,H,S,Dh] bf16, RoPE applied
// EPI 2: V -> [B,H,Dh,S] bf16 (transposed)
// EPI 3: fp32 [M,N] (final output)
template <int EPI>
__global__ __launch_bounds__(256) void gemm_bt(
    const unsigned short* __restrict__ A,  // [M,K] bf16
    const unsigned short* __restrict__ B,  // [N,K] bf16
    const float* __restrict__ bias,        // [N]
    const float2* __restrict__ tct,        // [SEQ][32] (cos,sin)
    unsigned short* __restrict__ outb,
    float* __restrict__ outf,
    int K) {
  __shared__ unsigned short As[128][32];
  __shared__ unsigned short Bs[128][32];
  const int bm = blockIdx.y * 128;
  const int bn = blockIdx.x * 128;
  const int tid = threadIdx.x;
  const int lane = tid & 63;
  const int w = tid >> 6;
  const int wr = (w >> 1) * 64, wc = (w & 1) * 64;
  const int fr = lane & 15;
  const int g = lane >> 4;
  const int fk = g * 8;
  const int srow0 = (w * 2) * 16 + (lane >> 2);
  const int srow1 = (w * 2 + 1) * 16 + (lane >> 2);
  const int scol = (lane & 3) * 8;

  f32x4 acc[4][4] = {};

  for (int k0 = 0; k0 < K; k0 += 32) {
    GLOAD_LDS16(&A[(size_t)(bm + srow0) * K + k0 + scol], &As[srow0][scol]);
    GLOAD_LDS16(&A[(size_t)(bm + srow1) * K + k0 + scol], &As[srow1][scol]);
    GLOAD_LDS16(&B[(size_t)(bn + srow0) * K + k0 + scol], &Bs[srow0][scol]);
    GLOAD_LDS16(&B[(size_t)(bn + srow1) * K + k0 + scol], &Bs[srow1][scol]);
    __syncthreads();
    short8 af[4], bf[4];
    for (int mi = 0; mi < 4; mi++)
      af[mi] = *(const short8*)&As[wr + mi * 16 + fr][fk];
    for (int ni = 0; ni < 4; ni++)
      bf[ni] = *(const short8*)&Bs[wc + ni * 16 + fr][fk];
    for (int mi = 0; mi < 4; mi++)
      for (int ni = 0; ni < 4; ni++)
        acc[mi][ni] = mfma16(af[mi], bf[ni], acc[mi][ni]);
    __syncthreads();
  }

  if (EPI <= 1) {
    // Q/K epilogue with fused RoPE. Wave's 64 cols = exactly one head.
    const float SC = (EPI == 0) ? 0.125f : 1.0f;
    const int h = (bn + wc) >> 6;
    for (int mi = 0; mi < 4; mi++)
      for (int r = 0; r < 4; r++) {
        int row = bm + wr + mi * 16 + g * 4 + r;
        int b = row >> 11, s = row & (SEQ - 1);
        size_t base = (((size_t)(b * NUM_HEADS + h)) * SEQ + s) * 64;
        for (int ni = 0; ni < 2; ni++) {
          int i = ni * 16 + fr;  // dh in [0,32)
          float x0 = acc[mi][ni][r] + bias[bn + wc + i];
          float x1 = acc[mi][ni + 2][r] + bias[bn + wc + i + 32];
          float2 cs = tct[s * 32 + i];
          outb[base + i]      = f2b((x0 * cs.x - x1 * cs.y) * SC);
          outb[base + i + 32] = f2b((x1 * cs.x + x0 * cs.y) * SC);
        }
      }
  } else {
    for (int mi = 0; mi < 4; mi++)
      for (int ni = 0; ni < 4; ni++)
        for (int r = 0; r < 4; r++) {
          int row = bm + wr + mi * 16 + g * 4 + r;
          int col = bn + wc + ni * 16 + fr;
          float v = acc[mi][ni][r] + bias[col];
          if (EPI == 3) {
            outf[(size_t)row * D_MODEL + col] = v;
          } else {
            int b = row >> 11, s = row & (SEQ - 1);
            int h = col >> 6, dh = col & 63;
            outb[(((size_t)(b * NUM_HEADS + h)) * 64 + dh) * SEQ + s] = f2b(v);
          }
        }
  }
}

// ---------------- causal flash attention ----------------
// 4 waves / block. Each block handles q-tiles {qb, 31-qb} sequentially
// (constant 33 kv-steps per block -> no causal imbalance).
// Swapped QK^T: mfma(K,Q) -> lane owns one q-row's scores in registers;
// softmax reduce = in-register + 2 shfl_xor.
#define KPAD 72  // 144B row stride

__global__ __launch_bounds__(256) void flash_attn(
    const unsigned short* __restrict__ Q,
    const unsigned short* __restrict__ Km,
    const unsigned short* __restrict__ Vt,
    unsigned short* __restrict__ ctx) {
  __shared__ unsigned short Ks[64][KPAD];      // [key][dh]
  __shared__ unsigned short Vs[64][KPAD];      // [dh][key]
  __shared__ unsigned short Ps[4][16][KPAD];   // per-wave P^T: [q][key]
  const int bh = blockIdx.y;   // 32
  const int tid = threadIdx.x;
  const int lane = tid & 63;
  const int w = tid >> 6;
  const int fr = lane & 15;
  const int g = lane >> 4;
  const int fk = g * 8;

  const unsigned short* Qp = Q + (size_t)bh * SEQ * 64;
  const unsigned short* Kp = Km + (size_t)bh * SEQ * 64;
  const unsigned short* Vp = Vt + (size_t)bh * 64 * SEQ;
  const int b = bh >> 4, h = bh & 15;

  for (int ph = 0; ph < 2; ph++) {
    const int qb = ph ? (31 - (int)blockIdx.x) : (int)blockIdx.x;
    const int qbase = qb * 64;
    const int qrow0 = qbase + w * 16;
    const int wmax = qrow0 + 15;
    const int q = qrow0 + fr;          // this lane's q-row (B-frag n-index)

    short8 qf0 = *(const short8*)&Qp[(size_t)q * 64 + fk];
    short8 qf1 = *(const short8*)&Qp[(size_t)q * 64 + 32 + fk];

    float mq = -INFINITY, lq = 0.f;
    f32x4 cacc[4] = {};

    for (int kbase = 0; kbase <= qbase; kbase += 64) {
      for (int i = 0; i < 2; i++) {
        int c = tid + 256 * i;
        int row = c >> 3, col = (c & 7) * 8;
        *(short8*)&Ks[row][col] = *(const short8*)&Kp[(size_t)(kbase + row) * 64 + col];
        *(short8*)&Vs[row][col] = *(const short8*)&Vp[(size_t)row * SEQ + kbase + col];
      }
      __syncthreads();

      // scores (transposed): D[key-offset][q] per 16x16 tile
      f32x4 sacc[4] = {};
      for (int n = 0; n < 4; n++) {
        if (kbase + n * 16 <= wmax) {
          short8 kf0 = *(const short8*)&Ks[n * 16 + fr][fk];
          short8 kf1 = *(const short8*)&Ks[n * 16 + fr][32 + fk];
          sacc[n] = mfma16(kf0, qf0, sacc[n]);
          sacc[n] = mfma16(kf1, qf1, sacc[n]);
        }
      }

      // mask + in-register online softmax (lane owns q-row)
      float sv[4][4];
      float mp = -INFINITY;
      for (int n = 0; n < 4; n++)
        for (int r = 0; r < 4; r++) {
          int key = kbase + n * 16 + g * 4 + r;
          sv[n][r] = (key <= q) ? sacc[n][r] : -INFINITY;
          mp = fmaxf(mp, sv[n][r]);
        }
      mp = fmaxf(mp, __shfl_xor(mp, 16));
      mp = fmaxf(mp, __shfl_xor(mp, 32));
      float mnew = fmaxf(mq, mp);
      float corr = __expf(mq - mnew);
      mq = mnew;
      float rs = 0.f;
      for (int n = 0; n < 4; n++)
        for (int r = 0; r < 4; r++) {
          float pv = __expf(sv[n][r] - mnew);
          sv[n][r] = pv;
          rs += pv;
        }
      rs += __shfl_xor(rs, 16);
      rs += __shfl_xor(rs, 32);
      lq = lq * corr + rs;

      // P^T -> LDS: Ps[q][key]
      for (int n = 0; n < 4; n++)
        for (int r = 0; r < 4; r++)
          Ps[w][fr][n * 16 + g * 4 + r] = f2b(sv[n][r]);

      // redistribute corr to PV accumulator layout (row q-offset = g*4+r)
      float corrR[4];
      for (int r = 0; r < 4; r++) corrR[r] = __shfl(corr, g * 4 + r);
      for (int db = 0; db < 4; db++)
        for (int r = 0; r < 4; r++) cacc[db][r] *= corrR[r];

      // PV: rows q (A-frag from Ps), cols d (B-frag from Vs)
      for (int ks = 0; ks < 2; ks++) {
        if (kbase + ks * 32 <= wmax) {
          short8 pa = *(const short8*)&Ps[w][fr][ks * 32 + fk];
          for (int db = 0; db < 4; db++) {
            short8 vf = *(const short8*)&Vs[db * 16 + fr][ks * 32 + fk];
            cacc[db] = mfma16(pa, vf, cacc[db]);
          }
        }
      }
      __syncthreads();
    }

    float lR[4];
    for (int r = 0; r < 4; r++) lR[r] = __shfl(lq, g * 4 + r);
    for (int r = 0; r < 4; r++) {
      int row = qrow0 + g * 4 + r;
      float inv = 1.f / lR[r];
      for (int db = 0; db < 4; db++)
        ctx[(((size_t)b * SEQ) + row) * D_MODEL + h * 64 + db * 16 + fr] =
            f2b(cacc[db][r] * inv);
    }
  }
}

extern "C" void kernel_launch(void* const* d_in, const int* in_sizes, int n_in,
                              void* d_out, int out_size, void* d_ws, size_t ws_size,
                              hipStream_t stream) {
  const float* x  = (const float*)d_in[0];
  const float* Wq = (const float*)d_in[1];
  const float* bq = (const float*)d_in[2];
  const float* Wk = (const float*)d_in[3];
  const float* bk = (const float*)d_in[4];
  const float* Wv = (const float*)d_in[5];
  const float* bv = (const float*)d_in[6];
  const float* Wo = (const float*)d_in[7];
  const float* bo = (const float*)d_in[8];
  float* out = (float*)d_out;

  char* ws = (char*)d_ws;
  size_t off = 0;
  auto alloc = [&](size_t bytes) {
    char* p = ws + off;
    off += (bytes + 255) & ~(size_t)255;
    return p;
  };
  unsigned short* xb   = (unsigned short*)alloc((size_t)MTOT * D_MODEL * 2);
  unsigned short* wqb  = (unsigned short*)alloc((size_t)D_MODEL * D_MODEL * 2);
  unsigned short* wkb  = (unsigned short*)alloc((size_t)D_MODEL * D_MODEL * 2);
  unsigned short* wvb  = (unsigned short*)alloc((size_t)D_MODEL * D_MODEL * 2);
  unsigned short* wob  = (unsigned short*)alloc((size_t)D_MODEL * D_MODEL * 2);
  unsigned short* Qb   = (unsigned short*)alloc((size_t)BH * SEQ * 64 * 2);
  unsigned short* Kb   = (unsigned short*)alloc((size_t)BH * SEQ * 64 * 2);
  unsigned short* Vt   = (unsigned short*)alloc((size_t)BH * 64 * SEQ * 2);
  unsigned short* ctxb = (unsigned short*)alloc((size_t)MTOT * D_MODEL * 2);
  float2* tct = (float2*)alloc((size_t)SEQ * 32 * 8);

  int nx = MTOT * D_MODEL;
  int nw = D_MODEL * D_MODEL;
  cvt_f32_bf16<<<nx / 1024, 256, 0, stream>>>(x, xb, nx);
  cvt4_f32_bf16<<<dim3(nw / 1024, 4), 256, 0, stream>>>(Wq, Wk, Wv, Wo, wqb, wkb, wvb, wob, nw);
  trig_kernel<<<SEQ * 32 / 256, 256, 0, stream>>>(tct);

  dim3 gg(D_MODEL / 128, MTOT / 128);
  gemm_bt<0><<<gg, 256, 0, stream>>>(xb, wqb, bq, tct, Qb, nullptr, D_MODEL);
  gemm_bt<1><<<gg, 256, 0, stream>>>(xb, wkb, bk, tct, Kb, nullptr, D_MODEL);
  gemm_bt<2><<<gg, 256, 0, stream>>>(xb, wvb, bv, tct, Vt, nullptr, D_MODEL);

  flash_attn<<<dim3(16, BH), 256, 0, stream>>>(Qb, Kb, Vt, ctxb);

  gemm_bt<3><<<gg, 256, 0, stream>>>(ctxb, wob, bo, tct, nullptr, out, D_MODEL);
}

// Round 4
// 149.900 us; speedup vs baseline: 2.3733x; 1.4580x over previous
//
#include <hip/hip_runtime.h>
#include <hip/hip_bf16.h>
#include <math.h>

typedef __attribute__((ext_vector_type(8))) short short8;
typedef __attribute__((ext_vector_type(8))) __bf16 bf16x8;
typedef __attribute__((ext_vector_type(4))) float f32x4;

#define D_MODEL 1024
#define NUM_HEADS 16
#define D_HEAD 64
#define BATCH 2
#define SEQ 2048
#define BH (BATCH * NUM_HEADS)   // 32
#define MTOT (BATCH * SEQ)       // 4096

__device__ inline f32x4 mfma16(short8 a, short8 b, f32x4 c) {
  return __builtin_amdgcn_mfma_f32_16x16x32_bf16(
      __builtin_bit_cast(bf16x8, a), __builtin_bit_cast(bf16x8, b), c, 0, 0, 0);
}

__device__ inline unsigned short f2b(float f) {
  __hip_bfloat16 h = __float2bfloat16(f);
  return __builtin_bit_cast(unsigned short, h);
}

__device__ inline unsigned cvt_pk_bf16(float lo, float hi) {
  unsigned r;
  asm("v_cvt_pk_bf16_f32 %0, %1, %2" : "=v"(r) : "v"(lo), "v"(hi));
  return r;
}

#define GLOAD_LDS16(gaddr, laddr)                                              \
  __builtin_amdgcn_global_load_lds(                                            \
      (const __attribute__((address_space(1))) void*)(gaddr),                  \
      (__attribute__((address_space(3))) void*)(laddr), 16, 0, 0)

// ---------------- fp32 -> bf16 conversion (vectorized) ----------------
__global__ void cvt_f32_bf16(const float* __restrict__ in,
                             unsigned short* __restrict__ out, int n) {
  int i = (blockIdx.x * 256 + threadIdx.x) * 4;
  if (i >= n) return;
  float4 v = *(const float4*)(in + i);
  ushort4 o;
  o.x = f2b(v.x); o.y = f2b(v.y); o.z = f2b(v.z); o.w = f2b(v.w);
  *(ushort4*)(out + i) = o;
}

// 4 equal-size weight matrices in one launch (blockIdx.y selects)
__global__ void cvt4_f32_bf16(const float* __restrict__ w0, const float* __restrict__ w1,
                              const float* __restrict__ w2, const float* __restrict__ w3,
                              unsigned short* __restrict__ o0, unsigned short* __restrict__ o1,
                              unsigned short* __restrict__ o2, unsigned short* __restrict__ o3,
                              int n) {
  const float* in; unsigned short* out;
  switch (blockIdx.y) {
    case 0: in = w0; out = o0; break;
    case 1: in = w1; out = o1; break;
    case 2: in = w2; out = o2; break;
    default: in = w3; out = o3; break;
  }
  int i = (blockIdx.x * 256 + threadIdx.x) * 4;
  if (i >= n) return;
  float4 v = *(const float4*)(in + i);
  ushort4 o;
  o.x = f2b(v.x); o.y = f2b(v.y); o.z = f2b(v.z); o.w = f2b(v.w);
  *(ushort4*)(out + i) = o;
}

// ---------------- RoPE table: interleaved (cos,sin), [SEQ][32] ----------------
__global__ void trig_kernel(float2* __restrict__ tct) {
  int idx = blockIdx.x * 256 + threadIdx.x;  // SEQ*32 threads
  int i = idx & 31;
  int s = idx >> 5;
  float inv = powf(10000.0f, -(float)i / 32.0f);
  float t = (float)s * inv;
  tct[idx] = make_float2(cosf(t), sinf(t));
}

// ---------------- merged QKV GEMM ----------------
// C[M, 3072] = x[M,1024] @ Wqkv[3072,1024]^T (+bias), double-buffered LDS.
// type = col>>10: 0 -> Q (RoPE, *0.125, [B,H,S,Dh]), 1 -> K (RoPE, [B,H,S,Dh]),
// 2 -> V (transpose to [B,H,Dh,S]).
__global__ __launch_bounds__(256) void gemm_qkv(
    const unsigned short* __restrict__ A,     // [M,1024] bf16
    const unsigned short* __restrict__ Wqkv,  // [3072,1024] bf16
    const float* __restrict__ bq, const float* __restrict__ bk,
    const float* __restrict__ bv,
    const float2* __restrict__ tct,
    unsigned short* __restrict__ Qb, unsigned short* __restrict__ Kb,
    unsigned short* __restrict__ Vt) {
  __shared__ unsigned short As[2][128][32];
  __shared__ unsigned short Bs[2][128][32];
  const int K = D_MODEL, NT = D_MODEL / 32;
  const int bm = blockIdx.y * 128;
  const int bn = blockIdx.x * 128;
  const int tid = threadIdx.x;
  const int lane = tid & 63;
  const int w = tid >> 6;
  const int wr = (w >> 1) * 64, wc = (w & 1) * 64;
  const int fr = lane & 15;
  const int g = lane >> 4;
  const int fk = g * 8;
  const int srow0 = (w * 2) * 16 + (lane >> 2);
  const int srow1 = (w * 2 + 1) * 16 + (lane >> 2);
  const int scol = (lane & 3) * 8;

  f32x4 acc[4][4] = {};

  GLOAD_LDS16(&A[(size_t)(bm + srow0) * K + scol], &As[0][srow0][scol]);
  GLOAD_LDS16(&A[(size_t)(bm + srow1) * K + scol], &As[0][srow1][scol]);
  GLOAD_LDS16(&Wqkv[(size_t)(bn + srow0) * K + scol], &Bs[0][srow0][scol]);
  GLOAD_LDS16(&Wqkv[(size_t)(bn + srow1) * K + scol], &Bs[0][srow1][scol]);
  __syncthreads();

  for (int t = 0; t < NT; ++t) {
    const int cur = t & 1;
    if (t + 1 < NT) {
      const int k0 = (t + 1) * 32;
      GLOAD_LDS16(&A[(size_t)(bm + srow0) * K + k0 + scol], &As[cur ^ 1][srow0][scol]);
      GLOAD_LDS16(&A[(size_t)(bm + srow1) * K + k0 + scol], &As[cur ^ 1][srow1][scol]);
      GLOAD_LDS16(&Wqkv[(size_t)(bn + srow0) * K + k0 + scol], &Bs[cur ^ 1][srow0][scol]);
      GLOAD_LDS16(&Wqkv[(size_t)(bn + srow1) * K + k0 + scol], &Bs[cur ^ 1][srow1][scol]);
    }
    short8 af[4], bf4[4];
    for (int mi = 0; mi < 4; mi++)
      af[mi] = *(const short8*)&As[cur][wr + mi * 16 + fr][fk];
    for (int ni = 0; ni < 4; ni++)
      bf4[ni] = *(const short8*)&Bs[cur][wc + ni * 16 + fr][fk];
    for (int mi = 0; mi < 4; mi++)
      for (int ni = 0; ni < 4; ni++)
        acc[mi][ni] = mfma16(af[mi], bf4[ni], acc[mi][ni]);
    __syncthreads();  // drains prefetch vmcnt + lds reads
  }

  const int type = bn >> 10;         // block-uniform
  const int cloc = (bn & 1023) + wc; // col within the 1024 group
  if (type <= 1) {
    const float* bias = (type == 0) ? bq : bk;
    unsigned short* outp = (type == 0) ? Qb : Kb;
    const float SC = (type == 0) ? 0.125f : 1.0f;
    const int h = cloc >> 6;
    for (int mi = 0; mi < 4; mi++)
      for (int r = 0; r < 4; r++) {
        int row = bm + wr + mi * 16 + g * 4 + r;
        int b = row >> 11, s = row & (SEQ - 1);
        size_t base = (((size_t)(b * NUM_HEADS + h)) * SEQ + s) * 64;
        for (int ni = 0; ni < 2; ni++) {
          int i = ni * 16 + fr;  // dh in [0,32)
          float x0 = acc[mi][ni][r] + bias[cloc + i];
          float x1 = acc[mi][ni + 2][r] + bias[cloc + i + 32];
          float2 cs = tct[s * 32 + i];
          outp[base + i]      = f2b((x0 * cs.x - x1 * cs.y) * SC);
          outp[base + i + 32] = f2b((x1 * cs.x + x0 * cs.y) * SC);
        }
      }
  } else {
    for (int mi = 0; mi < 4; mi++)
      for (int ni = 0; ni < 4; ni++)
        for (int r = 0; r < 4; r++) {
          int row = bm + wr + mi * 16 + g * 4 + r;
          int b = row >> 11, s = row & (SEQ - 1);
          int col = cloc + ni * 16 + fr;
          int h = col >> 6, dh = col & 63;
          float v = acc[mi][ni][r] + bv[col];
          Vt[(((size_t)(b * NUM_HEADS + h)) * 64 + dh) * SEQ + s] = f2b(v);
        }
  }
}

// ---------------- output GEMM: out[M,1024] = ctx @ Wo^T + bo (fp32) --------
__global__ __launch_bounds__(256) void gemm_out(
    const unsigned short* __restrict__ A,   // ctx bf16 [M,1024]
    const unsigned short* __restrict__ B,   // Wo bf16 [1024,1024]
    const float* __restrict__ bias,
    float* __restrict__ outf) {
  __shared__ unsigned short As[2][128][32];
  __shared__ unsigned short Bs[2][128][32];
  const int K = D_MODEL, NT = D_MODEL / 32;
  const int bm = blockIdx.y * 128;
  const int bn = blockIdx.x * 128;
  const int tid = threadIdx.x;
  const int lane = tid & 63;
  const int w = tid >> 6;
  const int wr = (w >> 1) * 64, wc = (w & 1) * 64;
  const int fr = lane & 15;
  const int g = lane >> 4;
  const int fk = g * 8;
  const int srow0 = (w * 2) * 16 + (lane >> 2);
  const int srow1 = (w * 2 + 1) * 16 + (lane >> 2);
  const int scol = (lane & 3) * 8;

  f32x4 acc[4][4] = {};

  GLOAD_LDS16(&A[(size_t)(bm + srow0) * K + scol], &As[0][srow0][scol]);
  GLOAD_LDS16(&A[(size_t)(bm + srow1) * K + scol], &As[0][srow1][scol]);
  GLOAD_LDS16(&B[(size_t)(bn + srow0) * K + scol], &Bs[0][srow0][scol]);
  GLOAD_LDS16(&B[(size_t)(bn + srow1) * K + scol], &Bs[0][srow1][scol]);
  __syncthreads();

  for (int t = 0; t < NT; ++t) {
    const int cur = t & 1;
    if (t + 1 < NT) {
      const int k0 = (t + 1) * 32;
      GLOAD_LDS16(&A[(size_t)(bm + srow0) * K + k0 + scol], &As[cur ^ 1][srow0][scol]);
      GLOAD_LDS16(&A[(size_t)(bm + srow1) * K + k0 + scol], &As[cur ^ 1][srow1][scol]);
      GLOAD_LDS16(&B[(size_t)(bn + srow0) * K + k0 + scol], &Bs[cur ^ 1][srow0][scol]);
      GLOAD_LDS16(&B[(size_t)(bn + srow1) * K + k0 + scol], &Bs[cur ^ 1][srow1][scol]);
    }
    short8 af[4], bf4[4];
    for (int mi = 0; mi < 4; mi++)
      af[mi] = *(const short8*)&As[cur][wr + mi * 16 + fr][fk];
    for (int ni = 0; ni < 4; ni++)
      bf4[ni] = *(const short8*)&Bs[cur][wc + ni * 16 + fr][fk];
    for (int mi = 0; mi < 4; mi++)
      for (int ni = 0; ni < 4; ni++)
        acc[mi][ni] = mfma16(af[mi], bf4[ni], acc[mi][ni]);
    __syncthreads();
  }

  for (int mi = 0; mi < 4; mi++)
    for (int ni = 0; ni < 4; ni++)
      for (int r = 0; r < 4; r++) {
        int row = bm + wr + mi * 16 + g * 4 + r;
        int col = bn + wc + ni * 16 + fr;
        outf[(size_t)row * D_MODEL + col] = acc[mi][ni][r] + bias[col];
      }
}

// ---------------- causal flash attention ----------------
// grid (bh=32, 32). One 64-row q-tile per block (qb = 31 - by: longest first).
// 4 waves x 16 q-rows. KVBLK=64 staged via reg-prefetch (T14). Swapped QK^T
// -> in-register softmax; defer-max (T13); diagonal-only masking; packed
// cvt_pk P writes.
#define KPAD 72  // 144B row stride

__global__ __launch_bounds__(256) void flash_attn(
    const unsigned short* __restrict__ Q,
    const unsigned short* __restrict__ Km,
    const unsigned short* __restrict__ Vt,
    unsigned short* __restrict__ ctx) {
  __shared__ unsigned short Ks[64][KPAD];      // [key][dh]
  __shared__ unsigned short Vs[64][KPAD];      // [dh][key]
  __shared__ unsigned short Ps[4][16][KPAD];   // per-wave P: [q][key]
  const int bh = blockIdx.x;
  const int qb = 31 - (int)blockIdx.y;   // longest blocks dispatch first
  const int tid = threadIdx.x;
  const int lane = tid & 63;
  const int w = tid >> 6;
  const int fr = lane & 15;
  const int g = lane >> 4;
  const int fk = g * 8;

  const unsigned short* Qp = Q + (size_t)bh * SEQ * 64;
  const unsigned short* Kp = Km + (size_t)bh * SEQ * 64;
  const unsigned short* Vp = Vt + (size_t)bh * 64 * SEQ;
  const int b = bh >> 4, h = bh & 15;

  const int qbase = qb * 64;
  const int qrow0 = qbase + w * 16;
  const int wmax = qrow0 + 15;
  const int q = qrow0 + fr;            // this lane's q-row

  short8 qf0 = *(const short8*)&Qp[(size_t)q * 64 + fk];
  short8 qf1 = *(const short8*)&Qp[(size_t)q * 64 + 32 + fk];

  // staging geometry (per thread, 2 chunks)
  const int c0 = tid, c1 = tid + 256;
  const int r0 = c0 >> 3, cc0 = (c0 & 7) * 8;
  const int r1 = c1 >> 3, cc1 = (c1 & 7) * 8;

  // prefetch tile 0
  short8 kr0 = *(const short8*)&Kp[(size_t)r0 * 64 + cc0];
  short8 kr1 = *(const short8*)&Kp[(size_t)r1 * 64 + cc1];
  short8 vr0 = *(const short8*)&Vp[(size_t)r0 * SEQ + cc0];
  short8 vr1 = *(const short8*)&Vp[(size_t)r1 * SEQ + cc1];

  float mq = -INFINITY, lq = 0.f;
  f32x4 cacc[4] = {};
  const int nsteps = qb + 1;

  for (int step = 0; step < nsteps; ++step) {
    const int kbase = step * 64;
    // write staged regs -> LDS
    *(short8*)&Ks[r0][cc0] = kr0;
    *(short8*)&Ks[r1][cc1] = kr1;
    *(short8*)&Vs[r0][cc0] = vr0;
    *(short8*)&Vs[r1][cc1] = vr1;
    __syncthreads();
    // issue next tile's loads (hidden under compute)
    if (step + 1 < nsteps) {
      const int nk = kbase + 64;
      kr0 = *(const short8*)&Kp[(size_t)(nk + r0) * 64 + cc0];
      kr1 = *(const short8*)&Kp[(size_t)(nk + r1) * 64 + cc1];
      vr0 = *(const short8*)&Vp[(size_t)r0 * SEQ + nk + cc0];
      vr1 = *(const short8*)&Vp[(size_t)r1 * SEQ + nk + cc1];
    }

    // QK^T (swapped): sacc[n] rows = keys, cols = q
    f32x4 sacc[4] = {};
    for (int n = 0; n < 4; n++) {
      if (kbase + n * 16 <= wmax) {
        short8 kf0 = *(const short8*)&Ks[n * 16 + fr][fk];
        short8 kf1 = *(const short8*)&Ks[n * 16 + fr][32 + fk];
        sacc[n] = mfma16(kf0, qf0, sacc[n]);
        sacc[n] = mfma16(kf1, qf1, sacc[n]);
      }
    }

    // mask (diagonal step only) + tile max
    const bool needMask = (kbase + 63 > qrow0);  // wave-uniform
    float sv[4][4];
    float mp = -INFINITY;
    if (needMask) {
      for (int n = 0; n < 4; n++)
        for (int r = 0; r < 4; r++) {
          int key = kbase + n * 16 + g * 4 + r;
          sv[n][r] = (key <= q) ? sacc[n][r] : -INFINITY;
          mp = fmaxf(mp, sv[n][r]);
        }
    } else {
      for (int n = 0; n < 4; n++)
        for (int r = 0; r < 4; r++) {
          sv[n][r] = sacc[n][r];
          mp = fmaxf(mp, sv[n][r]);
        }
    }
    mp = fmaxf(mp, __shfl_xor(mp, 16));
    mp = fmaxf(mp, __shfl_xor(mp, 32));

    // defer-max online softmax
    float rs = 0.f;
    if (__any(mp > mq + 8.0f)) {
      float mnew = fmaxf(mq, mp);
      float corr = __expf(mq - mnew);
      for (int n = 0; n < 4; n++)
        for (int r = 0; r < 4; r++) {
          sv[n][r] = __expf(sv[n][r] - mnew);
          rs += sv[n][r];
        }
      rs += __shfl_xor(rs, 16);
      rs += __shfl_xor(rs, 32);
      lq = lq * corr + rs;
      mq = mnew;
      float corrR[4];
      for (int r = 0; r < 4; r++) corrR[r] = __shfl(corr, g * 4 + r);
      for (int db = 0; db < 4; db++)
        for (int r = 0; r < 4; r++) cacc[db][r] *= corrR[r];
    } else {
      for (int n = 0; n < 4; n++)
        for (int r = 0; r < 4; r++) {
          sv[n][r] = __expf(sv[n][r] - mq);
          rs += sv[n][r];
        }
      rs += __shfl_xor(rs, 16);
      rs += __shfl_xor(rs, 32);
      lq += rs;
    }

    // packed P -> LDS: Ps[q=fr][key], 4 x ds_write_b64
    for (int n = 0; n < 4; n++) {
      unsigned p01 = cvt_pk_bf16(sv[n][0], sv[n][1]);
      unsigned p23 = cvt_pk_bf16(sv[n][2], sv[n][3]);
      *(uint2*)&Ps[w][fr][n * 16 + g * 4] = make_uint2(p01, p23);
    }

    // PV
    for (int ks = 0; ks < 2; ks++) {
      if (kbase + ks * 32 <= wmax) {
        short8 pa = *(const short8*)&Ps[w][fr][ks * 32 + fk];
        for (int db = 0; db < 4; db++) {
          short8 vf = *(const short8*)&Vs[db * 16 + fr][ks * 32 + fk];
          cacc[db] = mfma16(pa, vf, cacc[db]);
        }
      }
    }
    __syncthreads();
  }

  float lR[4];
  for (int r = 0; r < 4; r++) lR[r] = __shfl(lq, g * 4 + r);
  for (int r = 0; r < 4; r++) {
    int row = qrow0 + g * 4 + r;
    float inv = 1.f / lR[r];
    for (int db = 0; db < 4; db++)
      ctx[(((size_t)b * SEQ) + row) * D_MODEL + h * 64 + db * 16 + fr] =
          f2b(cacc[db][r] * inv);
  }
}

extern "C" void kernel_launch(void* const* d_in, const int* in_sizes, int n_in,
                              void* d_out, int out_size, void* d_ws, size_t ws_size,
                              hipStream_t stream) {
  const float* x  = (const float*)d_in[0];
  const float* Wq = (const float*)d_in[1];
  const float* bq = (const float*)d_in[2];
  const float* Wk = (const float*)d_in[3];
  const float* bk = (const float*)d_in[4];
  const float* Wv = (const float*)d_in[5];
  const float* bv = (const float*)d_in[6];
  const float* Wo = (const float*)d_in[7];
  const float* bo = (const float*)d_in[8];
  float* out = (float*)d_out;

  char* ws = (char*)d_ws;
  size_t off = 0;
  auto alloc = [&](size_t bytes) {
    char* p = ws + off;
    off += (bytes + 255) & ~(size_t)255;
    return p;
  };
  unsigned short* xb   = (unsigned short*)alloc((size_t)MTOT * D_MODEL * 2);
  unsigned short* wqkv = (unsigned short*)alloc((size_t)3 * D_MODEL * D_MODEL * 2);
  unsigned short* wob  = (unsigned short*)alloc((size_t)D_MODEL * D_MODEL * 2);
  unsigned short* Qb   = (unsigned short*)alloc((size_t)BH * SEQ * 64 * 2);
  unsigned short* Kb   = (unsigned short*)alloc((size_t)BH * SEQ * 64 * 2);
  unsigned short* Vt   = (unsigned short*)alloc((size_t)BH * 64 * SEQ * 2);
  unsigned short* ctxb = (unsigned short*)alloc((size_t)MTOT * D_MODEL * 2);
  float2* tct = (float2*)alloc((size_t)SEQ * 32 * 8);

  int nx = MTOT * D_MODEL;
  int nw = D_MODEL * D_MODEL;
  cvt_f32_bf16<<<nx / 1024, 256, 0, stream>>>(x, xb, nx);
  cvt4_f32_bf16<<<dim3(nw / 1024, 4), 256, 0, stream>>>(
      Wq, Wk, Wv, Wo, wqkv, wqkv + nw, wqkv + 2 * (size_t)nw, wob, nw);
  trig_kernel<<<SEQ * 32 / 256, 256, 0, stream>>>(tct);

  gemm_qkv<<<dim3(3 * D_MODEL / 128, MTOT / 128), 256, 0, stream>>>(
      xb, wqkv, bq, bk, bv, tct, Qb, Kb, Vt);

  flash_attn<<<dim3(BH, 32), 256, 0, stream>>>(Qb, Kb, Vt, ctxb);

  gemm_out<<<dim3(D_MODEL / 128, MTOT / 128), 256, 0, stream>>>(ctxb, wob, bo, out);
}

// Round 5
// 147.816 us; speedup vs baseline: 2.4067x; 1.0141x over previous
//
#include <hip/hip_runtime.h>
#include <hip/hip_bf16.h>
#include <math.h>

typedef __attribute__((ext_vector_type(8))) short short8;
typedef __attribute__((ext_vector_type(8))) __bf16 bf16x8;
typedef __attribute__((ext_vector_type(4))) float f32x4;

#define D_MODEL 1024
#define NUM_HEADS 16
#define D_HEAD 64
#define BATCH 2
#define SEQ 2048
#define BH (BATCH * NUM_HEADS)   // 32
#define MTOT (BATCH * SEQ)       // 4096

__device__ inline f32x4 mfma16(short8 a, short8 b, f32x4 c) {
  return __builtin_amdgcn_mfma_f32_16x16x32_bf16(
      __builtin_bit_cast(bf16x8, a), __builtin_bit_cast(bf16x8, b), c, 0, 0, 0);
}

__device__ inline unsigned short f2b(float f) {
  __hip_bfloat16 h = __float2bfloat16(f);
  return __builtin_bit_cast(unsigned short, h);
}

__device__ inline unsigned cvt_pk_bf16(float lo, float hi) {
  unsigned r;
  asm("v_cvt_pk_bf16_f32 %0, %1, %2" : "=v"(r) : "v"(lo), "v"(hi));
  return r;
}

// fused "wait own prefetch landed (leave N in flight) + barrier"; memory
// clobber keeps the compiler from moving LDS reads/VMEM issues across it.
__device__ __forceinline__ void wait_barrier_vm4() {
  asm volatile("s_waitcnt vmcnt(4)\n\ts_barrier" ::: "memory");
}
__device__ __forceinline__ void wait_barrier_vm0() {
  asm volatile("s_waitcnt vmcnt(0)\n\ts_barrier" ::: "memory");
}

#define GLOAD_LDS16(gaddr, laddr)                                              \
  __builtin_amdgcn_global_load_lds(                                            \
      (const __attribute__((address_space(1))) void*)(gaddr),                  \
      (__attribute__((address_space(3))) void*)(laddr), 16, 0, 0)

// ---------------- fp32 -> bf16 conversion (vectorized) ----------------
__global__ void cvt_f32_bf16(const float* __restrict__ in,
                             unsigned short* __restrict__ out, int n) {
  int i = (blockIdx.x * 256 + threadIdx.x) * 4;
  if (i >= n) return;
  float4 v = *(const float4*)(in + i);
  ushort4 o;
  o.x = f2b(v.x); o.y = f2b(v.y); o.z = f2b(v.z); o.w = f2b(v.w);
  *(ushort4*)(out + i) = o;
}

// 4 equal-size weight matrices in one launch (blockIdx.y selects)
__global__ void cvt4_f32_bf16(const float* __restrict__ w0, const float* __restrict__ w1,
                              const float* __restrict__ w2, const float* __restrict__ w3,
                              unsigned short* __restrict__ o0, unsigned short* __restrict__ o1,
                              unsigned short* __restrict__ o2, unsigned short* __restrict__ o3,
                              int n) {
  const float* in; unsigned short* out;
  switch (blockIdx.y) {
    case 0: in = w0; out = o0; break;
    case 1: in = w1; out = o1; break;
    case 2: in = w2; out = o2; break;
    default: in = w3; out = o3; break;
  }
  int i = (blockIdx.x * 256 + threadIdx.x) * 4;
  if (i >= n) return;
  float4 v = *(const float4*)(in + i);
  ushort4 o;
  o.x = f2b(v.x); o.y = f2b(v.y); o.z = f2b(v.z); o.w = f2b(v.w);
  *(ushort4*)(out + i) = o;
}

// ---------------- RoPE table: interleaved (cos,sin), [SEQ][32] ----------------
__global__ void trig_kernel(float2* __restrict__ tct) {
  int idx = blockIdx.x * 256 + threadIdx.x;  // SEQ*32 threads
  int i = idx & 31;
  int s = idx >> 5;
  float inv = powf(10000.0f, -(float)i / 32.0f);
  float t = (float)s * inv;
  tct[idx] = make_float2(cosf(t), sinf(t));
}

// stage one 128x32 K-slab of A and B into LDS buffer `bufi`
#define STAGE_T(t, bufi)                                                        \
  do {                                                                          \
    const int _k0 = (t) * 32;                                                   \
    GLOAD_LDS16(&A[(size_t)(bm + srow0) * D_MODEL + _k0 + scol], &As[bufi][srow0][scol]); \
    GLOAD_LDS16(&A[(size_t)(bm + srow1) * D_MODEL + _k0 + scol], &As[bufi][srow1][scol]); \
    GLOAD_LDS16(&Bp[(size_t)(bn + srow0) * D_MODEL + _k0 + scol], &Bs[bufi][srow0][scol]); \
    GLOAD_LDS16(&Bp[(size_t)(bn + srow1) * D_MODEL + _k0 + scol], &Bs[bufi][srow1][scol]); \
  } while (0)

// depth-2 pipelined K-loop (3 buffers, counted vmcnt, raw barrier, setprio)
#define KLOOP_PIPE()                                                            \
  do {                                                                          \
    const int NT = D_MODEL / 32;                                                \
    STAGE_T(0, 0);                                                              \
    STAGE_T(1, 1);                                                              \
    for (int t = 0; t < NT; ++t) {                                              \
      if (t + 1 < NT) wait_barrier_vm4(); else wait_barrier_vm0();              \
      if (t + 2 < NT) STAGE_T(t + 2, (t + 2) % 3);                              \
      const int cur = t % 3;                                                    \
      short8 af[4], bf4[4];                                                     \
      for (int mi = 0; mi < 4; mi++)                                            \
        af[mi] = *(const short8*)&As[cur][wr + mi * 16 + fr][fk];               \
      for (int ni = 0; ni < 4; ni++)                                            \
        bf4[ni] = *(const short8*)&Bs[cur][wc + ni * 16 + fr][fk];              \
      __builtin_amdgcn_s_setprio(1);                                            \
      for (int mi = 0; mi < 4; mi++)                                            \
        for (int ni = 0; ni < 4; ni++)                                          \
          acc[mi][ni] = mfma16(af[mi], bf4[ni], acc[mi][ni]);                   \
      __builtin_amdgcn_s_setprio(0);                                            \
    }                                                                           \
  } while (0)

// ---------------- merged QKV GEMM ----------------
// C[M, 3072] = x[M,1024] @ Wqkv[3072,1024]^T (+bias).
// type = col>>10: 0 -> Q (RoPE, *0.125, [B,H,S,Dh]), 1 -> K (RoPE, [B,H,S,Dh]),
// 2 -> V (transpose to [B,H,Dh,S], packed 8B stores).
__global__ __launch_bounds__(256) void gemm_qkv(
    const unsigned short* __restrict__ A,     // [M,1024] bf16
    const unsigned short* __restrict__ Bp,    // Wqkv [3072,1024] bf16
    const float* __restrict__ bq, const float* __restrict__ bk,
    const float* __restrict__ bv,
    const float2* __restrict__ tct,
    unsigned short* __restrict__ Qb, unsigned short* __restrict__ Kb,
    unsigned short* __restrict__ Vt) {
  __shared__ unsigned short As[3][128][32];
  __shared__ unsigned short Bs[3][128][32];
  // XCD-aware swizzle: 768 blocks, 96 consecutive per XCD -> A-rows L2-local
  int id = blockIdx.y * 24 + blockIdx.x;
  id = (id & 7) * 96 + (id >> 3);
  const int bm = (id / 24) * 128;
  const int bn = (id % 24) * 128;
  const int tid = threadIdx.x;
  const int lane = tid & 63;
  const int w = tid >> 6;
  const int wr = (w >> 1) * 64, wc = (w & 1) * 64;
  const int fr = lane & 15;
  const int g = lane >> 4;
  const int fk = g * 8;
  const int srow0 = (w * 2) * 16 + (lane >> 2);
  const int srow1 = (w * 2 + 1) * 16 + (lane >> 2);
  const int scol = (lane & 3) * 8;

  f32x4 acc[4][4] = {};
  KLOOP_PIPE();

  const int type = bn >> 10;         // block-uniform
  const int cloc = (bn & 1023) + wc; // col within the 1024 group
  if (type <= 1) {
    const float* bias = (type == 0) ? bq : bk;
    unsigned short* outp = (type == 0) ? Qb : Kb;
    const float SC = (type == 0) ? 0.125f : 1.0f;
    const int h = cloc >> 6;
    for (int mi = 0; mi < 4; mi++)
      for (int r = 0; r < 4; r++) {
        int row = bm + wr + mi * 16 + g * 4 + r;
        int b = row >> 11, s = row & (SEQ - 1);
        size_t base = (((size_t)(b * NUM_HEADS + h)) * SEQ + s) * 64;
        for (int ni = 0; ni < 2; ni++) {
          int i = ni * 16 + fr;  // dh in [0,32)
          float x0 = acc[mi][ni][r] + bias[cloc + i];
          float x1 = acc[mi][ni + 2][r] + bias[cloc + i + 32];
          float2 cs = tct[s * 32 + i];
          outp[base + i]      = f2b((x0 * cs.x - x1 * cs.y) * SC);
          outp[base + i + 32] = f2b((x1 * cs.x + x0 * cs.y) * SC);
        }
      }
  } else {
    for (int mi = 0; mi < 4; mi++) {
      int row0 = bm + wr + mi * 16 + g * 4;   // 4 consecutive s, same b
      int b = row0 >> 11, s0 = row0 & (SEQ - 1);
      for (int ni = 0; ni < 4; ni++) {
        int col = cloc + ni * 16 + fr;
        int h = col >> 6, dh = col & 63;
        float bvv = bv[col];
        uint2 pk = make_uint2(
            cvt_pk_bf16(acc[mi][ni][0] + bvv, acc[mi][ni][1] + bvv),
            cvt_pk_bf16(acc[mi][ni][2] + bvv, acc[mi][ni][3] + bvv));
        *(uint2*)&Vt[(((size_t)(b * NUM_HEADS + h)) * 64 + dh) * SEQ + s0] = pk;
      }
    }
  }
}

// ---------------- output GEMM: out[M,1024] = ctx @ Wo^T + bo (fp32) --------
__global__ __launch_bounds__(256) void gemm_out(
    const unsigned short* __restrict__ A,   // ctx bf16 [M,1024]
    const unsigned short* __restrict__ Bp,  // Wo bf16 [1024,1024]
    const float* __restrict__ bias,
    float* __restrict__ outf) {
  __shared__ unsigned short As[3][128][32];
  __shared__ unsigned short Bs[3][128][32];
  // XCD swizzle: 256 blocks, 32 consecutive per XCD
  int id = blockIdx.y * 8 + blockIdx.x;
  id = (id & 7) * 32 + (id >> 3);
  const int bm = (id / 8) * 128;
  const int bn = (id % 8) * 128;
  const int tid = threadIdx.x;
  const int lane = tid & 63;
  const int w = tid >> 6;
  const int wr = (w >> 1) * 64, wc = (w & 1) * 64;
  const int fr = lane & 15;
  const int g = lane >> 4;
  const int fk = g * 8;
  const int srow0 = (w * 2) * 16 + (lane >> 2);
  const int srow1 = (w * 2 + 1) * 16 + (lane >> 2);
  const int scol = (lane & 3) * 8;

  f32x4 acc[4][4] = {};
  KLOOP_PIPE();

  for (int mi = 0; mi < 4; mi++)
    for (int ni = 0; ni < 4; ni++)
      for (int r = 0; r < 4; r++) {
        int row = bm + wr + mi * 16 + g * 4 + r;
        int col = bn + wc + ni * 16 + fr;
        outf[(size_t)row * D_MODEL + col] = acc[mi][ni][r] + bias[col];
      }
}

// ---------------- causal flash attention ----------------
// grid (bh=32, 32). One 64-row q-tile per block (qb = 31 - by: longest first).
// 4 waves x 16 q-rows. KVBLK=64 staged via reg-prefetch (T14). Swapped QK^T
// -> in-register softmax; defer-max (T13); diagonal-only masking; packed
// cvt_pk P writes.
#define KPAD 72  // 144B row stride

__global__ __launch_bounds__(256) void flash_attn(
    const unsigned short* __restrict__ Q,
    const unsigned short* __restrict__ Km,
    const unsigned short* __restrict__ Vt,
    unsigned short* __restrict__ ctx) {
  __shared__ unsigned short Ks[64][KPAD];      // [key][dh]
  __shared__ unsigned short Vs[64][KPAD];      // [dh][key]
  __shared__ unsigned short Ps[4][16][KPAD];   // per-wave P: [q][key]
  const int bh = blockIdx.x;
  const int qb = 31 - (int)blockIdx.y;   // longest blocks dispatch first
  const int tid = threadIdx.x;
  const int lane = tid & 63;
  const int w = tid >> 6;
  const int fr = lane & 15;
  const int g = lane >> 4;
  const int fk = g * 8;

  const unsigned short* Qp = Q + (size_t)bh * SEQ * 64;
  const unsigned short* Kp = Km + (size_t)bh * SEQ * 64;
  const unsigned short* Vp = Vt + (size_t)bh * 64 * SEQ;
  const int b = bh >> 4, h = bh & 15;

  const int qbase = qb * 64;
  const int qrow0 = qbase + w * 16;
  const int wmax = qrow0 + 15;
  const int q = qrow0 + fr;            // this lane's q-row

  short8 qf0 = *(const short8*)&Qp[(size_t)q * 64 + fk];
  short8 qf1 = *(const short8*)&Qp[(size_t)q * 64 + 32 + fk];

  // staging geometry (per thread, 2 chunks)
  const int c0 = tid, c1 = tid + 256;
  const int r0 = c0 >> 3, cc0 = (c0 & 7) * 8;
  const int r1 = c1 >> 3, cc1 = (c1 & 7) * 8;

  // prefetch tile 0
  short8 kr0 = *(const short8*)&Kp[(size_t)r0 * 64 + cc0];
  short8 kr1 = *(const short8*)&Kp[(size_t)r1 * 64 + cc1];
  short8 vr0 = *(const short8*)&Vp[(size_t)r0 * SEQ + cc0];
  short8 vr1 = *(const short8*)&Vp[(size_t)r1 * SEQ + cc1];

  float mq = -INFINITY, lq = 0.f;
  f32x4 cacc[4] = {};
  const int nsteps = qb + 1;

  for (int step = 0; step < nsteps; ++step) {
    const int kbase = step * 64;
    // write staged regs -> LDS
    *(short8*)&Ks[r0][cc0] = kr0;
    *(short8*)&Ks[r1][cc1] = kr1;
    *(short8*)&Vs[r0][cc0] = vr0;
    *(short8*)&Vs[r1][cc1] = vr1;
    __syncthreads();
    // issue next tile's loads (hidden under compute)
    if (step + 1 < nsteps) {
      const int nk = kbase + 64;
      kr0 = *(const short8*)&Kp[(size_t)(nk + r0) * 64 + cc0];
      kr1 = *(const short8*)&Kp[(size_t)(nk + r1) * 64 + cc1];
      vr0 = *(const short8*)&Vp[(size_t)r0 * SEQ + nk + cc0];
      vr1 = *(const short8*)&Vp[(size_t)r1 * SEQ + nk + cc1];
    }

    // QK^T (swapped): sacc[n] rows = keys, cols = q
    f32x4 sacc[4] = {};
    for (int n = 0; n < 4; n++) {
      if (kbase + n * 16 <= wmax) {
        short8 kf0 = *(const short8*)&Ks[n * 16 + fr][fk];
        short8 kf1 = *(const short8*)&Ks[n * 16 + fr][32 + fk];
        sacc[n] = mfma16(kf0, qf0, sacc[n]);
        sacc[n] = mfma16(kf1, qf1, sacc[n]);
      }
    }

    // mask (diagonal step only) + tile max
    const bool needMask = (kbase + 63 > qrow0);  // wave-uniform
    float sv[4][4];
    float mp = -INFINITY;
    if (needMask) {
      for (int n = 0; n < 4; n++)
        for (int r = 0; r < 4; r++) {
          int key = kbase + n * 16 + g * 4 + r;
          sv[n][r] = (key <= q) ? sacc[n][r] : -INFINITY;
          mp = fmaxf(mp, sv[n][r]);
        }
    } else {
      for (int n = 0; n < 4; n++)
        for (int r = 0; r < 4; r++) {
          sv[n][r] = sacc[n][r];
          mp = fmaxf(mp, sv[n][r]);
        }
    }
    mp = fmaxf(mp, __shfl_xor(mp, 16));
    mp = fmaxf(mp, __shfl_xor(mp, 32));

    // defer-max online softmax
    float rs = 0.f;
    if (__any(mp > mq + 8.0f)) {
      float mnew = fmaxf(mq, mp);
      float corr = __expf(mq - mnew);
      for (int n = 0; n < 4; n++)
        for (int r = 0; r < 4; r++) {
          sv[n][r] = __expf(sv[n][r] - mnew);
          rs += sv[n][r];
        }
      rs += __shfl_xor(rs, 16);
      rs += __shfl_xor(rs, 32);
      lq = lq * corr + rs;
      mq = mnew;
      float corrR[4];
      for (int r = 0; r < 4; r++) corrR[r] = __shfl(corr, g * 4 + r);
      for (int db = 0; db < 4; db++)
        for (int r = 0; r < 4; r++) cacc[db][r] *= corrR[r];
    } else {
      for (int n = 0; n < 4; n++)
        for (int r = 0; r < 4; r++) {
          sv[n][r] = __expf(sv[n][r] - mq);
          rs += sv[n][r];
        }
      rs += __shfl_xor(rs, 16);
      rs += __shfl_xor(rs, 32);
      lq += rs;
    }

    // packed P -> LDS: Ps[q=fr][key], 4 x ds_write_b64
    for (int n = 0; n < 4; n++) {
      unsigned p01 = cvt_pk_bf16(sv[n][0], sv[n][1]);
      unsigned p23 = cvt_pk_bf16(sv[n][2], sv[n][3]);
      *(uint2*)&Ps[w][fr][n * 16 + g * 4] = make_uint2(p01, p23);
    }

    // PV
    for (int ks = 0; ks < 2; ks++) {
      if (kbase + ks * 32 <= wmax) {
        short8 pa = *(const short8*)&Ps[w][fr][ks * 32 + fk];
        for (int db = 0; db < 4; db++) {
          short8 vf = *(const short8*)&Vs[db * 16 + fr][ks * 32 + fk];
          cacc[db] = mfma16(pa, vf, cacc[db]);
        }
      }
    }
    __syncthreads();
  }

  float lR[4];
  for (int r = 0; r < 4; r++) lR[r] = __shfl(lq, g * 4 + r);
  for (int r = 0; r < 4; r++) {
    int row = qrow0 + g * 4 + r;
    float inv = 1.f / lR[r];
    for (int db = 0; db < 4; db++)
      ctx[(((size_t)b * SEQ) + row) * D_MODEL + h * 64 + db * 16 + fr] =
          f2b(cacc[db][r] * inv);
  }
}

extern "C" void kernel_launch(void* const* d_in, const int* in_sizes, int n_in,
                              void* d_out, int out_size, void* d_ws, size_t ws_size,
                              hipStream_t stream) {
  const float* x  = (const float*)d_in[0];
  const float* Wq = (const float*)d_in[1];
  const float* bq = (const float*)d_in[2];
  const float* Wk = (const float*)d_in[3];
  const float* bk = (const float*)d_in[4];
  const float* Wv = (const float*)d_in[5];
  const float* bv = (const float*)d_in[6];
  const float* Wo = (const float*)d_in[7];
  const float* bo = (const float*)d_in[8];
  float* out = (float*)d_out;

  char* ws = (char*)d_ws;
  size_t off = 0;
  auto alloc = [&](size_t bytes) {
    char* p = ws + off;
    off += (bytes + 255) & ~(size_t)255;
    return p;
  };
  unsigned short* xb   = (unsigned short*)alloc((size_t)MTOT * D_MODEL * 2);
  unsigned short* wqkv = (unsigned short*)alloc((size_t)3 * D_MODEL * D_MODEL * 2);
  unsigned short* wob  = (unsigned short*)alloc((size_t)D_MODEL * D_MODEL * 2);
  unsigned short* Qb   = (unsigned short*)alloc((size_t)BH * SEQ * 64 * 2);
  unsigned short* Kb   = (unsigned short*)alloc((size_t)BH * SEQ * 64 * 2);
  unsigned short* Vt   = (unsigned short*)alloc((size_t)BH * 64 * SEQ * 2);
  unsigned short* ctxb = (unsigned short*)alloc((size_t)MTOT * D_MODEL * 2);
  float2* tct = (float2*)alloc((size_t)SEQ * 32 * 8);

  int nx = MTOT * D_MODEL;
  int nw = D_MODEL * D_MODEL;
  cvt_f32_bf16<<<nx / 1024, 256, 0, stream>>>(x, xb, nx);
  cvt4_f32_bf16<<<dim3(nw / 1024, 4), 256, 0, stream>>>(
      Wq, Wk, Wv, Wo, wqkv, wqkv + nw, wqkv + 2 * (size_t)nw, wob, nw);
  trig_kernel<<<SEQ * 32 / 256, 256, 0, stream>>>(tct);

  gemm_qkv<<<dim3(3 * D_MODEL / 128, MTOT / 128), 256, 0, stream>>>(
      xb, wqkv, bq, bk, bv, tct, Qb, Kb, Vt);

  flash_attn<<<dim3(BH, 32), 256, 0, stream>>>(Qb, Kb, Vt, ctxb);

  gemm_out<<<dim3(D_MODEL / 128, MTOT / 128), 256, 0, stream>>>(ctxb, wob, bo, out);
}

// Round 6
// 130.269 us; speedup vs baseline: 2.7309x; 1.1347x over previous
//
#include <hip/hip_runtime.h>
#include <hip/hip_bf16.h>
#include <math.h>

typedef __attribute__((ext_vector_type(8))) short short8;
typedef __attribute__((ext_vector_type(8))) __bf16 bf16x8;
typedef __attribute__((ext_vector_type(4))) float f32x4;

#define D_MODEL 1024
#define NUM_HEADS 16
#define D_HEAD 64
#define BATCH 2
#define SEQ 2048
#define BH (BATCH * NUM_HEADS)   // 32
#define MTOT (BATCH * SEQ)       // 4096

__device__ inline f32x4 mfma16(short8 a, short8 b, f32x4 c) {
  return __builtin_amdgcn_mfma_f32_16x16x32_bf16(
      __builtin_bit_cast(bf16x8, a), __builtin_bit_cast(bf16x8, b), c, 0, 0, 0);
}

__device__ inline unsigned short f2b(float f) {
  __hip_bfloat16 h = __float2bfloat16(f);
  return __builtin_bit_cast(unsigned short, h);
}

__device__ inline unsigned cvt_pk_bf16(float lo, float hi) {
  unsigned r;
  asm("v_cvt_pk_bf16_f32 %0, %1, %2" : "=v"(r) : "v"(lo), "v"(hi));
  return r;
}

// single drain+barrier per K-tile (m248 2-phase minimum). memory clobber
// keeps LDS reads / VMEM issues from crossing.
__device__ __forceinline__ void wait_barrier_vm0() {
  asm volatile("s_waitcnt vmcnt(0)\n\ts_barrier" ::: "memory");
}

#define GLOAD_LDS16(gaddr, laddr)                                              \
  __builtin_amdgcn_global_load_lds(                                            \
      (const __attribute__((address_space(1))) void*)(gaddr),                  \
      (__attribute__((address_space(3))) void*)(laddr), 16, 0, 0)

// ---------------- fp32 -> bf16 conversion (vectorized) ----------------
__global__ void cvt_f32_bf16(const float* __restrict__ in,
                             unsigned short* __restrict__ out, int n) {
  int i = (blockIdx.x * 256 + threadIdx.x) * 4;
  if (i >= n) return;
  float4 v = *(const float4*)(in + i);
  ushort4 o;
  o.x = f2b(v.x); o.y = f2b(v.y); o.z = f2b(v.z); o.w = f2b(v.w);
  *(ushort4*)(out + i) = o;
}

// 4 equal-size weight matrices in one launch (blockIdx.y selects)
__global__ void cvt4_f32_bf16(const float* __restrict__ w0, const float* __restrict__ w1,
                              const float* __restrict__ w2, const float* __restrict__ w3,
                              unsigned short* __restrict__ o0, unsigned short* __restrict__ o1,
                              unsigned short* __restrict__ o2, unsigned short* __restrict__ o3,
                              int n) {
  const float* in; unsigned short* out;
  switch (blockIdx.y) {
    case 0: in = w0; out = o0; break;
    case 1: in = w1; out = o1; break;
    case 2: in = w2; out = o2; break;
    default: in = w3; out = o3; break;
  }
  int i = (blockIdx.x * 256 + threadIdx.x) * 4;
  if (i >= n) return;
  float4 v = *(const float4*)(in + i);
  ushort4 o;
  o.x = f2b(v.x); o.y = f2b(v.y); o.z = f2b(v.z); o.w = f2b(v.w);
  *(ushort4*)(out + i) = o;
}

// ---------------- RoPE table: interleaved (cos,sin), [SEQ][32] ----------------
__global__ void trig_kernel(float2* __restrict__ tct) {
  int idx = blockIdx.x * 256 + threadIdx.x;  // SEQ*32 threads
  int i = idx & 31;
  int s = idx >> 5;
  float inv = powf(10000.0f, -(float)i / 32.0f);
  float t = (float)s * inv;
  tct[idx] = make_float2(cosf(t), sinf(t));
}

// ---- BK=64 staging: linear LDS dest (gload_lds requirement), XOR-swizzled
// GLOBAL source. LDS slot s=(lane&7) of row r holds global col-slot s^(r&7);
// reader XORs the same way (involution).
#define STAGE64(t, bufi)                                                        \
  do {                                                                          \
    const int _k0 = (t) * 64;                                                   \
    const int _gc = ((lane & 7) ^ (lane >> 3)) * 8;                             \
    const int _lc = (lane & 7) * 8;                                             \
    for (int j = 0; j < 4; j++) {                                               \
      const int _r = w * 32 + j * 8 + (lane >> 3);                              \
      GLOAD_LDS16(&A[(size_t)(bm + _r) * D_MODEL + _k0 + _gc], &As[bufi][_r][_lc]); \
      GLOAD_LDS16(&Bp[(size_t)(bn + _r) * D_MODEL + _k0 + _gc], &Bs[bufi][_r][_lc]); \
    }                                                                           \
  } while (0)

// 2-phase pipelined K-loop: ONE vmcnt(0)+barrier per K-tile; prefetch of t+1
// stays in flight across the whole compute phase.
#define KLOOP64()                                                               \
  do {                                                                          \
    const int NT = D_MODEL / 64;                                                \
    STAGE64(0, 0);                                                              \
    for (int t = 0; t < NT; ++t) {                                              \
      const int cur = t & 1;                                                    \
      wait_barrier_vm0();                                                       \
      if (t + 1 < NT) STAGE64(t + 1, cur ^ 1);                                  \
      for (int kk = 0; kk < 2; kk++) {                                          \
        short8 af[4], bf4[4];                                                   \
        for (int mi = 0; mi < 4; mi++)                                          \
          af[mi] = *(const short8*)&As[cur][wr + mi * 16 + fr]                  \
                                         [(kk * 32 + fk) ^ ((fr & 7) << 3)];    \
        for (int ni = 0; ni < 4; ni++)                                          \
          bf4[ni] = *(const short8*)&Bs[cur][wc + ni * 16 + fr]                 \
                                          [(kk * 32 + fk) ^ ((fr & 7) << 3)];   \
        __builtin_amdgcn_s_setprio(1);                                          \
        for (int mi = 0; mi < 4; mi++)                                          \
          for (int ni = 0; ni < 4; ni++)                                        \
            acc[mi][ni] = mfma16(af[mi], bf4[ni], acc[mi][ni]);                 \
        __builtin_amdgcn_s_setprio(0);                                          \
      }                                                                         \
    }                                                                           \
  } while (0)

// ---------------- merged QKV GEMM ----------------
// C[M, 3072] = x[M,1024] @ Wqkv[3072,1024]^T (+bias).
// type = col>>10: 0 -> Q (RoPE, *0.125, [B,H,S,Dh]), 1 -> K (RoPE, [B,H,S,Dh]),
// 2 -> V (transpose to [B,H,Dh,S], packed 8B stores).
__global__ __launch_bounds__(256) void gemm_qkv(
    const unsigned short* __restrict__ A,     // [M,1024] bf16
    const unsigned short* __restrict__ Bp,    // Wqkv [3072,1024] bf16
    const float* __restrict__ bq, const float* __restrict__ bk,
    const float* __restrict__ bv,
    const float2* __restrict__ tct,
    unsigned short* __restrict__ Qb, unsigned short* __restrict__ Kb,
    unsigned short* __restrict__ Vt) {
  __shared__ unsigned short As[2][128][64];
  __shared__ unsigned short Bs[2][128][64];
  const int bm = blockIdx.y * 128;
  const int bn = blockIdx.x * 128;
  const int tid = threadIdx.x;
  const int lane = tid & 63;
  const int w = tid >> 6;
  const int wr = (w >> 1) * 64, wc = (w & 1) * 64;
  const int fr = lane & 15;
  const int g = lane >> 4;
  const int fk = g * 8;

  f32x4 acc[4][4] = {};
  KLOOP64();

  const int type = bn >> 10;         // block-uniform
  const int cloc = (bn & 1023) + wc; // col within the 1024 group
  if (type <= 1) {
    const float* bias = (type == 0) ? bq : bk;
    unsigned short* outp = (type == 0) ? Qb : Kb;
    const float SC = (type == 0) ? 0.125f : 1.0f;
    const int h = cloc >> 6;
    for (int mi = 0; mi < 4; mi++)
      for (int r = 0; r < 4; r++) {
        int row = bm + wr + mi * 16 + g * 4 + r;
        int b = row >> 11, s = row & (SEQ - 1);
        size_t base = (((size_t)(b * NUM_HEADS + h)) * SEQ + s) * 64;
        for (int ni = 0; ni < 2; ni++) {
          int i = ni * 16 + fr;  // dh in [0,32)
          float x0 = acc[mi][ni][r] + bias[cloc + i];
          float x1 = acc[mi][ni + 2][r] + bias[cloc + i + 32];
          float2 cs = tct[s * 32 + i];
          outp[base + i]      = f2b((x0 * cs.x - x1 * cs.y) * SC);
          outp[base + i + 32] = f2b((x1 * cs.x + x0 * cs.y) * SC);
        }
      }
  } else {
    for (int mi = 0; mi < 4; mi++) {
      int row0 = bm + wr + mi * 16 + g * 4;   // 4 consecutive s, same b
      int b = row0 >> 11, s0 = row0 & (SEQ - 1);
      for (int ni = 0; ni < 4; ni++) {
        int col = cloc + ni * 16 + fr;
        int h = col >> 6, dh = col & 63;
        float bvv = bv[col];
        uint2 pk = make_uint2(
            cvt_pk_bf16(acc[mi][ni][0] + bvv, acc[mi][ni][1] + bvv),
            cvt_pk_bf16(acc[mi][ni][2] + bvv, acc[mi][ni][3] + bvv));
        *(uint2*)&Vt[(((size_t)(b * NUM_HEADS + h)) * 64 + dh) * SEQ + s0] = pk;
      }
    }
  }
}

// ---------------- output GEMM: out[M,1024] = ctx @ Wo^T + bo (fp32) --------
__global__ __launch_bounds__(256) void gemm_out(
    const unsigned short* __restrict__ A,   // ctx bf16 [M,1024]
    const unsigned short* __restrict__ Bp,  // Wo bf16 [1024,1024]
    const float* __restrict__ bias,
    float* __restrict__ outf) {
  __shared__ unsigned short As[2][128][64];
  __shared__ unsigned short Bs[2][128][64];
  const int bm = blockIdx.y * 128;
  const int bn = blockIdx.x * 128;
  const int tid = threadIdx.x;
  const int lane = tid & 63;
  const int w = tid >> 6;
  const int wr = (w >> 1) * 64, wc = (w & 1) * 64;
  const int fr = lane & 15;
  const int g = lane >> 4;
  const int fk = g * 8;

  f32x4 acc[4][4] = {};
  KLOOP64();

  for (int mi = 0; mi < 4; mi++)
    for (int ni = 0; ni < 4; ni++)
      for (int r = 0; r < 4; r++) {
        int row = bm + wr + mi * 16 + g * 4 + r;
        int col = bn + wc + ni * 16 + fr;
        outf[(size_t)row * D_MODEL + col] = acc[mi][ni][r] + bias[col];
      }
}

// ---------------- causal flash attention ----------------
// 512 threads = 8 waves: waves 0-3 -> q-tile 2j, waves 4-7 -> q-tile 2j+1,
// sharing the staged K/V tiles (8-way amortization). grid (bh=32, 16),
// longest pairs first. Per-wave: swapped QK^T in-reg softmax, defer-max,
// diagonal-only masking, packed cvt_pk P writes (verified R4 path).
#define KPAD 72  // 144B row stride

__global__ __launch_bounds__(512) void flash_attn(
    const unsigned short* __restrict__ Q,
    const unsigned short* __restrict__ Km,
    const unsigned short* __restrict__ Vt,
    unsigned short* __restrict__ ctx) {
  __shared__ unsigned short Ks[64][KPAD];      // [key][dh]
  __shared__ unsigned short Vs[64][KPAD];      // [dh][key]
  __shared__ unsigned short Ps[8][16][KPAD];   // per-wave P: [q][key]
  const int bh = blockIdx.x;
  const int qb0 = 30 - 2 * (int)blockIdx.y;    // heaviest pairs first
  const int tid = threadIdx.x;
  const int lane = tid & 63;
  const int w = tid >> 6;                      // 0..7
  const int gi = w >> 2;                       // wave-group: 0 or 1
  const int fr = lane & 15;
  const int g = lane >> 4;
  const int fk = g * 8;

  const unsigned short* Qp = Q + (size_t)bh * SEQ * 64;
  const unsigned short* Kp = Km + (size_t)bh * SEQ * 64;
  const unsigned short* Vp = Vt + (size_t)bh * 64 * SEQ;
  const int b = bh >> 4, h = bh & 15;

  const int qb = qb0 + gi;
  const int qrow0 = qb * 64 + (w & 3) * 16;
  const int wmax = qrow0 + 15;
  const int q = qrow0 + fr;            // this lane's q-row

  short8 qf0 = *(const short8*)&Qp[(size_t)q * 64 + fk];
  short8 qf1 = *(const short8*)&Qp[(size_t)q * 64 + 32 + fk];

  // staging geometry: 512 threads, one short8 each for K and V
  const int r0 = tid >> 3, cc0 = (tid & 7) * 8;

  // prefetch tile 0
  short8 kr = *(const short8*)&Kp[(size_t)r0 * 64 + cc0];
  short8 vr = *(const short8*)&Vp[(size_t)r0 * SEQ + cc0];

  float mq = -INFINITY, lq = 0.f;
  f32x4 cacc[4] = {};
  const int NSTEPS = qb0 + 2;          // block-uniform

  for (int step = 0; step < NSTEPS; ++step) {
    const int kbase = step * 64;
    // write staged regs -> LDS
    *(short8*)&Ks[r0][cc0] = kr;
    *(short8*)&Vs[r0][cc0] = vr;
    __syncthreads();
    // issue next tile's loads (hidden under compute)
    if (step + 1 < NSTEPS) {
      const int nk = kbase + 64;
      kr = *(const short8*)&Kp[(size_t)(nk + r0) * 64 + cc0];
      vr = *(const short8*)&Vp[(size_t)r0 * SEQ + nk + cc0];
    }

    if (kbase <= wmax) {  // wave-uniform: skip steps beyond this wave's range
      // QK^T (swapped): sacc[n] rows = keys, cols = q
      f32x4 sacc[4] = {};
      for (int n = 0; n < 4; n++) {
        if (kbase + n * 16 <= wmax) {
          short8 kf0 = *(const short8*)&Ks[n * 16 + fr][fk];
          short8 kf1 = *(const short8*)&Ks[n * 16 + fr][32 + fk];
          sacc[n] = mfma16(kf0, qf0, sacc[n]);
          sacc[n] = mfma16(kf1, qf1, sacc[n]);
        }
      }

      // mask (diagonal step only) + tile max
      const bool needMask = (kbase + 63 > qrow0);  // wave-uniform
      float sv[4][4];
      float mp = -INFINITY;
      if (needMask) {
        for (int n = 0; n < 4; n++)
          for (int r = 0; r < 4; r++) {
            int key = kbase + n * 16 + g * 4 + r;
            sv[n][r] = (key <= q) ? sacc[n][r] : -INFINITY;
            mp = fmaxf(mp, sv[n][r]);
          }
      } else {
        for (int n = 0; n < 4; n++)
          for (int r = 0; r < 4; r++) {
            sv[n][r] = sacc[n][r];
            mp = fmaxf(mp, sv[n][r]);
          }
      }
      mp = fmaxf(mp, __shfl_xor(mp, 16));
      mp = fmaxf(mp, __shfl_xor(mp, 32));

      // defer-max online softmax
      float rs = 0.f;
      if (__any(mp > mq + 8.0f)) {
        float mnew = fmaxf(mq, mp);
        float corr = __expf(mq - mnew);
        for (int n = 0; n < 4; n++)
          for (int r = 0; r < 4; r++) {
            sv[n][r] = __expf(sv[n][r] - mnew);
            rs += sv[n][r];
          }
        rs += __shfl_xor(rs, 16);
        rs += __shfl_xor(rs, 32);
        lq = lq * corr + rs;
        mq = mnew;
        float corrR[4];
        for (int r = 0; r < 4; r++) corrR[r] = __shfl(corr, g * 4 + r);
        for (int db = 0; db < 4; db++)
          for (int r = 0; r < 4; r++) cacc[db][r] *= corrR[r];
      } else {
        for (int n = 0; n < 4; n++)
          for (int r = 0; r < 4; r++) {
            sv[n][r] = __expf(sv[n][r] - mq);
            rs += sv[n][r];
          }
        rs += __shfl_xor(rs, 16);
        rs += __shfl_xor(rs, 32);
        lq += rs;
      }

      // packed P -> LDS: Ps[q=fr][key], 4 x ds_write_b64
      for (int n = 0; n < 4; n++) {
        unsigned p01 = cvt_pk_bf16(sv[n][0], sv[n][1]);
        unsigned p23 = cvt_pk_bf16(sv[n][2], sv[n][3]);
        *(uint2*)&Ps[w][fr][n * 16 + g * 4] = make_uint2(p01, p23);
      }

      // PV
      for (int ks = 0; ks < 2; ks++) {
        if (kbase + ks * 32 <= wmax) {
          short8 pa = *(const short8*)&Ps[w][fr][ks * 32 + fk];
          for (int db = 0; db < 4; db++) {
            short8 vf = *(const short8*)&Vs[db * 16 + fr][ks * 32 + fk];
            cacc[db] = mfma16(pa, vf, cacc[db]);
          }
        }
      }
    }
    __syncthreads();
  }

  float lR[4];
  for (int r = 0; r < 4; r++) lR[r] = __shfl(lq, g * 4 + r);
  for (int r = 0; r < 4; r++) {
    int row = qrow0 + g * 4 + r;
    float inv = 1.f / lR[r];
    for (int db = 0; db < 4; db++)
      ctx[(((size_t)b * SEQ) + row) * D_MODEL + h * 64 + db * 16 + fr] =
          f2b(cacc[db][r] * inv);
  }
}

extern "C" void kernel_launch(void* const* d_in, const int* in_sizes, int n_in,
                              void* d_out, int out_size, void* d_ws, size_t ws_size,
                              hipStream_t stream) {
  const float* x  = (const float*)d_in[0];
  const float* Wq = (const float*)d_in[1];
  const float* bq = (const float*)d_in[2];
  const float* Wk = (const float*)d_in[3];
  const float* bk = (const float*)d_in[4];
  const float* Wv = (const float*)d_in[5];
  const float* bv = (const float*)d_in[6];
  const float* Wo = (const float*)d_in[7];
  const float* bo = (const float*)d_in[8];
  float* out = (float*)d_out;

  char* ws = (char*)d_ws;
  size_t off = 0;
  auto alloc = [&](size_t bytes) {
    char* p = ws + off;
    off += (bytes + 255) & ~(size_t)255;
    return p;
  };
  unsigned short* xb   = (unsigned short*)alloc((size_t)MTOT * D_MODEL * 2);
  unsigned short* wqkv = (unsigned short*)alloc((size_t)3 * D_MODEL * D_MODEL * 2);
  unsigned short* wob  = (unsigned short*)alloc((size_t)D_MODEL * D_MODEL * 2);
  unsigned short* Qb   = (unsigned short*)alloc((size_t)BH * SEQ * 64 * 2);
  unsigned short* Kb   = (unsigned short*)alloc((size_t)BH * SEQ * 64 * 2);
  unsigned short* Vt   = (unsigned short*)alloc((size_t)BH * 64 * SEQ * 2);
  unsigned short* ctxb = (unsigned short*)alloc((size_t)MTOT * D_MODEL * 2);
  float2* tct = (float2*)alloc((size_t)SEQ * 32 * 8);

  int nx = MTOT * D_MODEL;
  int nw = D_MODEL * D_MODEL;
  cvt_f32_bf16<<<nx / 1024, 256, 0, stream>>>(x, xb, nx);
  cvt4_f32_bf16<<<dim3(nw / 1024, 4), 256, 0, stream>>>(
      Wq, Wk, Wv, Wo, wqkv, wqkv + nw, wqkv + 2 * (size_t)nw, wob, nw);
  trig_kernel<<<SEQ * 32 / 256, 256, 0, stream>>>(tct);

  gemm_qkv<<<dim3(3 * D_MODEL / 128, MTOT / 128), 256, 0, stream>>>(
      xb, wqkv, bq, bk, bv, tct, Qb, Kb, Vt);

  flash_attn<<<dim3(BH, 16), 512, 0, stream>>>(Qb, Kb, Vt, ctxb);

  gemm_out<<<dim3(D_MODEL / 128, MTOT / 128), 256, 0, stream>>>(ctxb, wob, bo, out);
}